// Round 9
// baseline (210.701 us; speedup 1.0000x reference)
//
#include <hip/hip_runtime.h>
#include <cstddef>
#include <cstdint>

#define LEAKY(s) ((s) >= 0.f ? (s) : 0.1f * (s))

constexpr int PTS    = 4096;   // H*W
constexpr int NBATCH = 32;
constexpr int NM     = 8;      // regions
constexpr int TILE   = 128;    // points per block in kA
constexpr int NTILES = PTS / TILE;  // 32

// ---------------- workspace layout (bytes) ----------------
constexpr size_t OFF_POOL = 0;        // pool (B,1024) u32 (enc f32) 128KB
constexpr size_t OFF_WSP  = 131072;   // split weights w2h/w2l/w3h/w3l 128KB
constexpr size_t OFF_Y32  = 262144;   // y32 (B,32,1024) f32 4MB

using bf16x8 = __attribute__((ext_vector_type(8))) short;
using f32x4v = __attribute__((ext_vector_type(4))) float;
using u16x4  = __attribute__((ext_vector_type(4))) unsigned short;
using u16x8  = __attribute__((ext_vector_type(8))) unsigned short;

// split f32 -> bf16 hi (truncate) + bf16 lo (RNE of remainder): x ~ hi + lo
__device__ __forceinline__ void splitbf(float x, unsigned short& h, unsigned short& l) {
  unsigned u = __float_as_uint(x);
  unsigned short hh = (unsigned short)(u >> 16);
  float r = x - __uint_as_float((unsigned)hh << 16);
  unsigned v = __float_as_uint(r);
  unsigned rr = (v + 0x7FFFu + ((v >> 16) & 1u)) >> 16;
  h = hh; l = (unsigned short)rr;
}

// monotone f32 <-> u32 encoding (order-preserving) for atomicMax pooling
__device__ __forceinline__ unsigned encf(float f) {
  unsigned u = __float_as_uint(f);
  return (u & 0x80000000u) ? ~u : (u | 0x80000000u);
}
__device__ __forceinline__ float decf(unsigned e) {
  unsigned u = (e & 0x80000000u) ? (e ^ 0x80000000u) : ~e;
  return __uint_as_float(u);
}

// swizzled byte offset into Xt[pt][k] bf16 arrays (row = 256B): XOR bits 4..6 by pt&7
__device__ __forceinline__ int swzb(int pt, int kByte) {
  return pt * 256 + (kByte ^ ((pt & 7) << 4));
}

// ============================================================
// Kernel W: pre-split w2/w3 into bf16 hi/lo planes in A-fragment order
// AND zero the pool. grid(128),256.
// elem = (((mt*4+kt)*4+l4)*16+l15)*8+e ; c=mt*16+l15, k=kt*32+l4*8+e
// ============================================================
__global__ __launch_bounds__(256) void kW(const float* __restrict__ w2,
                                          const float* __restrict__ w3,
                                          unsigned short* __restrict__ wsp,
                                          unsigned* __restrict__ pool) {
  int id = blockIdx.x * 256 + threadIdx.x;   // 0..32767
  pool[id] = 0u;                             // enc(x) > 0 for all finite x
  int layer = id >> 14, e16 = id & 16383;
  int e = e16 & 7, l15 = (e16 >> 3) & 15, l4 = (e16 >> 7) & 3,
      kt = (e16 >> 9) & 3, mt = e16 >> 11;
  int c = mt * 16 + l15, k = kt * 32 + l4 * 8 + e;
  float v = (layer ? w3 : w2)[c * 128 + k];
  unsigned short h, l;
  splitbf(v, h, l);
  wsp[layer * 32768 + e16] = h;
  wsp[layer * 32768 + 16384 + e16] = l;
}

// ============================================================
// Kernel A: conv1 -> conv2 -> conv3 (split-bf16 MFMA, POINT-SPLIT waves) ->
// masked-max -> atomicMax pool. grid (NTILES=32, B), 256 thr, 2 blocks/CU.
// Wave wv owns points [32wv, 32wv+32) x ALL 128 channels (mi=8, nt=2):
// B-fragment ds_reads = 16/wave/layer (was 64); A-fragments stream from L2.
// ============================================================
__device__ __forceinline__ void mfmaLayerP(const unsigned short* __restrict__ Wh,
                                           const unsigned short* __restrict__ Wl,
                                           const float* __restrict__ bias,
                                           const char* XHc, const char* XLc,
                                           int lane, int wv, f32x4v acc[8][2]) {
  const int l15 = lane & 15, l4 = lane >> 4;
#pragma unroll
  for (int mi = 0; mi < 8; mi++) {
    float4 bv = *(const float4*)(bias + mi * 16 + l4 * 4);
    f32x4v b4; b4[0] = bv.x; b4[1] = bv.y; b4[2] = bv.z; b4[3] = bv.w;
    acc[mi][0] = b4;
    acc[mi][1] = b4;
  }
#pragma unroll
  for (int kt = 0; kt < 4; kt++) {
    const int kb = (kt * 32 + l4 * 8) * 2;
    bf16x8 bh[2], bl[2];
#pragma unroll
    for (int ntl = 0; ntl < 2; ntl++) {
      const int off = swzb((wv * 2 + ntl) * 16 + l15, kb);
      bh[ntl] = *(const bf16x8*)(XHc + off);
      bl[ntl] = *(const bf16x8*)(XLc + off);
    }
#pragma unroll
    for (int mi = 0; mi < 8; mi++) {
      int off = (((mi * 4 + kt) * 4 + l4) * 16 + l15) * 8;
      bf16x8 ah = *(const bf16x8*)(Wh + off);
      bf16x8 al = *(const bf16x8*)(Wl + off);
#pragma unroll
      for (int ntl = 0; ntl < 2; ntl++) {
        acc[mi][ntl] = __builtin_amdgcn_mfma_f32_16x16x32_bf16(ah, bh[ntl], acc[mi][ntl], 0, 0, 0);
        acc[mi][ntl] = __builtin_amdgcn_mfma_f32_16x16x32_bf16(ah, bl[ntl], acc[mi][ntl], 0, 0, 0);
        acc[mi][ntl] = __builtin_amdgcn_mfma_f32_16x16x32_bf16(al, bh[ntl], acc[mi][ntl], 0, 0, 0);
      }
    }
  }
}

__global__ __launch_bounds__(256, 2) void kA(
    const float* __restrict__ coor, const float* __restrict__ region,
    const float* __restrict__ extents,
    const float* __restrict__ w1, const float* __restrict__ b1,
    const float* __restrict__ b2, const float* __restrict__ b3,
    const unsigned short* __restrict__ wsp,
    unsigned* __restrict__ pool) {
  __shared__ unsigned short XH[128 * 128];  // 32KB (f32 funnel aliases in epilogue)
  __shared__ unsigned short XL[128 * 128];  // 32KB
  __shared__ float reg_s[NM * TILE];        // 4KB
  const int tid = threadIdx.x;
  const int b = blockIdx.y;
  const int t0 = blockIdx.x * TILE;
  const int lane = tid & 63;
  const int wv = tid >> 6;
  char* XHc = (char*)XH;
  char* XLc = (char*)XL;

  {  // stage region tile: 8 rows x 128
    int m = tid >> 5, j = tid & 31;
    float4 v = *(const float4*)(region + ((size_t)b * NM + m) * PTS + t0 + j * 4);
    *(float4*)(reg_s + m * TILE + j * 4) = v;
  }
  {  // layer 1 (K=5): thread = (pt, ch-half); writes Xt bf16 hi/lo
    const int pt = tid & 127;
    const int chh = (tid >> 7) * 64;
    float e0 = extents[b * 3], e1 = extents[b * 3 + 1], e2 = extents[b * 3 + 2];
    float in5[5];
#pragma unroll
    for (int i = 0; i < 5; i++) in5[i] = coor[((size_t)b * 5 + i) * PTS + t0 + pt];
    in5[0] = (in5[0] - 0.5f) * e0;
    in5[1] = (in5[1] - 0.5f) * e1;
    in5[2] = (in5[2] - 0.5f) * e2;
    for (int c8 = 0; c8 < 64; c8 += 8) {
      u16x8 hh, ll;
#pragma unroll
      for (int q = 0; q < 8; q++) {
        int c = chh + c8 + q;
        float s = b1[c];
#pragma unroll
        for (int i = 0; i < 5; i++) s = fmaf(w1[c * 5 + i], in5[i], s);
        s = LEAKY(s);
        unsigned short h, l;
        splitbf(s, h, l);
        hh[q] = h; ll[q] = l;
      }
      int off = swzb(pt, (chh + c8) * 2);
      *(u16x8*)(XHc + off) = hh;
      *(u16x8*)(XLc + off) = ll;
    }
  }
  __syncthreads();

  f32x4v acc[8][2];
  const int l15 = lane & 15, l4 = lane >> 4;

  // layer 2
  mfmaLayerP(wsp, wsp + 16384, b2, XHc, XLc, lane, wv, acc);
  __syncthreads();
  {  // leaky + split + write act2 back to Xt (wave-local points)
#pragma unroll
    for (int mi = 0; mi < 8; mi++) {
      const int ch0 = mi * 16 + l4 * 4;
#pragma unroll
      for (int ntl = 0; ntl < 2; ntl++) {
        u16x4 h4, l4v;
#pragma unroll
        for (int r = 0; r < 4; r++) {
          float s = acc[mi][ntl][r];
          s = LEAKY(s);
          unsigned short h, l;
          splitbf(s, h, l);
          h4[r] = h; l4v[r] = l;
        }
        int off = swzb((wv * 2 + ntl) * 16 + l15, ch0 * 2);
        *(u16x4*)(XHc + off) = h4;
        *(u16x4*)(XLc + off) = l4v;
      }
    }
  }
  __syncthreads();
  // layer 3 (bias, no activation)
  mfmaLayerP(wsp + 32768, wsp + 49152, b3, XHc, XLc, lane, wv, acc);
  __syncthreads();  // all Xt reads done; reuse XH as f32 funnel [wv][ch][m]

  {  // region-masked max over the wave's 32 points -> funnel
    float* funnel = (float*)XH;
#pragma unroll
    for (int m = 0; m < NM; m++) {
      float rv0 = reg_s[m * TILE + (wv * 2 + 0) * 16 + l15];
      float rv1 = reg_s[m * TILE + (wv * 2 + 1) * 16 + l15];
#pragma unroll
      for (int mi = 0; mi < 8; mi++)
#pragma unroll
        for (int r = 0; r < 4; r++) {
          float mx = fmaxf(acc[mi][0][r] * rv0, acc[mi][1][r] * rv1);
          mx = fmaxf(mx, __shfl_xor(mx, 1));
          mx = fmaxf(mx, __shfl_xor(mx, 2));
          mx = fmaxf(mx, __shfl_xor(mx, 4));
          mx = fmaxf(mx, __shfl_xor(mx, 8));
          if (l15 == 0) funnel[(wv * 128 + mi * 16 + l4 * 4 + r) * 8 + m] = mx;
        }
    }
  }
  __syncthreads();
  {  // reduce over 4 waves + order-independent atomicMax pool
    const float* fun = (const float*)XH;
#pragma unroll
    for (int q = 0; q < 4; q++) {
      int pair = tid + q * 256;  // = ch*8 + m
      float mx = fun[pair];
      mx = fmaxf(mx, fun[1024 + pair]);
      mx = fmaxf(mx, fun[2048 + pair]);
      mx = fmaxf(mx, fun[3072 + pair]);
      atomicMax(pool + (size_t)b * 1024 + pair, encf(mx));
    }
  }
}

// ============================================================
// Kernel C: decode pool -> softmax (4 batches, in LDS) -> per-k sort ->
// GEMM D[b,k,m,o] = sum_c xs[c,m]*w_sp[o,c,k] -> fused gather-sum -> y32.
// grid (32 ktiles of 4, 8 bgroups of 4), 256 thr.
// T14 async-stage: issue next c0 chunk's global loads BEFORE compute.
// ============================================================
__global__ __launch_bounds__(256) void kC(const unsigned* __restrict__ pool,
                                          const float* __restrict__ w_sp,
                                          float* __restrict__ y32) {
  __shared__ float As[16 * 516];     // 33KB
  __shared__ float xsl[4 * 128 * 8]; // 16KB  [bl][c][m]
  __shared__ int idxL[4][4][8];      // [bl][kk][r]
  const int tid = threadIdx.x;
  const int k0 = blockIdx.x * 4;
  const int bbase = blockIdx.y * 4;
  const int rg = tid & 63, cgq = tid >> 6;

  // decode pool (4 b x 1024) -> xsl
#pragma unroll
  for (int it = 0; it < 4; it++) {
    uint4 v = *(const uint4*)(pool + (size_t)(bbase + it) * 1024 + tid * 4);
    float4 f = {decf(v.x), decf(v.y), decf(v.z), decf(v.w)};
    *(float4*)(xsl + it * 1024 + tid * 4) = f;
  }
  // prologue: issue c0=0 staging loads
  float4 wreg[8];
#pragma unroll
  for (int it = 0; it < 8; it++) {
    int q = tid + it * 256, o = q >> 4, cc = q & 15;
    wreg[it] = *(const float4*)(w_sp + (size_t)o * 16384 + (size_t)cc * 128 + k0);
  }
  __syncthreads();
  {  // softmax over c per (bl, m): 32 pairs x 8 threads
    int pair = tid >> 3, sub = tid & 7;
    int bl = pair >> 3, m = pair & 7;
    float* base = xsl + bl * 1024 + m;
    float v[16];
#pragma unroll
    for (int j = 0; j < 16; j++) v[j] = base[(sub + 8 * j) * 8];
    float mx = v[0];
#pragma unroll
    for (int j = 1; j < 16; j++) mx = fmaxf(mx, v[j]);
    mx = fmaxf(mx, __shfl_xor(mx, 1));
    mx = fmaxf(mx, __shfl_xor(mx, 2));
    mx = fmaxf(mx, __shfl_xor(mx, 4));
    float s = 0.f;
#pragma unroll
    for (int j = 0; j < 16; j++) { v[j] = expf(v[j] - mx); s += v[j]; }
    s += __shfl_xor(s, 1);
    s += __shfl_xor(s, 2);
    s += __shfl_xor(s, 4);
    float inv = 1.f / s;
#pragma unroll
    for (int j = 0; j < 16; j++) base[(sub + 8 * j) * 8] = v[j] * inv;
  }
  __syncthreads();
  if (tid < 16) {  // sort this block's 4 k-channels per batch
    int bl = tid >> 2, kk = tid & 3;
    float vv[8];
#pragma unroll
    for (int n = 0; n < 8; n++) vv[n] = xsl[bl * 1024 + (k0 + kk) * 8 + n];
    int used = 0;
#pragma unroll
    for (int n = 0; n < 8; n++) {
      int best = 0; float bv = -1.f;
#pragma unroll
      for (int q = 0; q < 8; q++) {
        bool ok = ((used >> q) & 1) == 0;
        if (ok && vv[q] > bv) { bv = vv[q]; best = q; }  // strict > == lowest-index tie-break
      }
      used |= 1 << best;
      idxL[bl][kk][n] = best;
    }
  }

  float acc[8][8];
#pragma unroll
  for (int i = 0; i < 8; i++)
#pragma unroll
    for (int j = 0; j < 8; j++) acc[i][j] = 0.f;

  for (int c0 = 0; c0 < 128; c0 += 16) {
    __syncthreads();  // As free (consumed by previous compute)
#pragma unroll
    for (int it = 0; it < 8; it++) {
      int q = tid + it * 256, o = q >> 4, cc = q & 15;
      As[cc * 516 + o]       = wreg[it].x;
      As[cc * 516 + 128 + o] = wreg[it].y;
      As[cc * 516 + 256 + o] = wreg[it].z;
      As[cc * 516 + 384 + o] = wreg[it].w;
    }
    __syncthreads();
    if (c0 + 16 < 128) {  // issue next chunk early (hidden under compute)
#pragma unroll
      for (int it = 0; it < 8; it++) {
        int q = tid + it * 256, o = q >> 4, cc = q & 15;
        wreg[it] = *(const float4*)(w_sp + (size_t)o * 16384 + (size_t)(c0 + 16 + cc) * 128 + k0);
      }
    }
#pragma unroll
    for (int cc = 0; cc < 16; cc++) {
      float4 a0 = *(const float4*)(As + cc * 516 + rg * 4);
      float4 a1 = *(const float4*)(As + cc * 516 + 256 + rg * 4);
      float4 p0 = *(const float4*)(xsl + cgq * 1024 + (c0 + cc) * 8);      // broadcast
      float4 p1 = *(const float4*)(xsl + cgq * 1024 + (c0 + cc) * 8 + 4);  // broadcast
      float av[8] = {a0.x, a0.y, a0.z, a0.w, a1.x, a1.y, a1.z, a1.w};
      float bv[8] = {p0.x, p0.y, p0.z, p0.w, p1.x, p1.y, p1.z, p1.w};
#pragma unroll
      for (int i = 0; i < 8; i++)
#pragma unroll
        for (int j = 0; j < 8; j++) acc[i][j] = fmaf(av[i], bv[j], acc[i][j]);
    }
  }
  // gather-sum epilogue. acc rows: i<4 -> row rg*4+i (kk=rg>>5, o=row&127);
  // i>=4 -> row 256+rg*4+(i-4) (kk=2+(rg>>5)). wave cgq owns batch bbase+cgq.
  const int rgl = rg & 31;
  const int kkA = rg >> 5;
  int msA[8], msB[8];
#pragma unroll
  for (int r = 0; r < 8; r++) {
    msA[r] = idxL[cgq][kkA][r];
    msB[r] = idxL[cgq][2 + kkA][r];
  }
  float yp[4][8];
#pragma unroll
  for (int i4 = 0; i4 < 4; i4++) {
#pragma unroll
    for (int r = 0; r < 8; r++) {
      float v = 0.f;
#pragma unroll
      for (int j = 0; j < 8; j++) {
        v += (j == msA[r]) ? acc[i4][j] : 0.f;
        v += (j == msB[r]) ? acc[i4 + 4][j] : 0.f;
      }
      yp[i4][r] = v;
    }
  }
#pragma unroll
  for (int i4 = 0; i4 < 4; i4++)
#pragma unroll
    for (int r = 0; r < 8; r++) yp[i4][r] += __shfl_xor(yp[i4][r], 32);
  if (rg < 32) {  // lane rg holds o = rg*4+i4, summed over 4 kk
    float* dst = y32 + ((size_t)(bbase + cgq) * 32 + blockIdx.x) * 1024 + rgl * 32;
#pragma unroll
    for (int i4 = 0; i4 < 4; i4++) {
      float4 v0 = {yp[i4][0], yp[i4][1], yp[i4][2], yp[i4][3]};
      float4 v1 = {yp[i4][4], yp[i4][5], yp[i4][6], yp[i4][7]};
      *(float4*)(dst + i4 * 8) = v0;
      *(float4*)(dst + i4 * 8 + 4) = v1;
    }
  }
}

// ============================================================
// Kernel E: assemble y (sum 32 tiles + b_sp + leaky) -> fc1 -> fc2 -> heads.
// grid (B), 1024 thr (16 waves).
// ============================================================
__global__ __launch_bounds__(1024) void kE(
    const float* __restrict__ y32, const float* __restrict__ b_sp,
    const float* __restrict__ fc1_w, const float* __restrict__ fc1_b,
    const float* __restrict__ fc2_w, const float* __restrict__ fc2_b,
    const float* __restrict__ fcr_w, const float* __restrict__ fcr_b,
    const float* __restrict__ fct_w, const float* __restrict__ fct_b,
    float* __restrict__ out) {
  __shared__ float yl[1024];
  __shared__ float h1[512];
  __shared__ float h2[256];
  int b = blockIdx.x, tid = threadIdx.x;
  int w = tid >> 6, lane = tid & 63;
  {  // assemble y: thread per feature
    const float* base = y32 + (size_t)b * 32768 + tid;
    float s = 0.f;
#pragma unroll 8
    for (int t = 0; t < 32; t++) s += base[t * 1024];
    s += b_sp[tid >> 3];
    yl[tid] = LEAKY(s);
  }
  __syncthreads();
  {  // fc1: 16 waves x 32 outputs
    const float4* ylv = (const float4*)yl;
    float4 u[4];
#pragma unroll
    for (int r = 0; r < 4; r++) u[r] = ylv[r * 64 + lane];
#pragma unroll 2
    for (int pass = 0; pass < 32; pass++) {
      int o = w * 32 + pass;
      const float4* wr = (const float4*)(fc1_w + (size_t)o * 1024);
      float sa = 0, sb = 0, sc = 0, sd = 0;
#pragma unroll
      for (int r = 0; r < 4; r++) {
        float4 wv = wr[r * 64 + lane];
        sa = fmaf(wv.x, u[r].x, sa); sb = fmaf(wv.y, u[r].y, sb);
        sc = fmaf(wv.z, u[r].z, sc); sd = fmaf(wv.w, u[r].w, sd);
      }
      float s = (sa + sb) + (sc + sd);
#pragma unroll
      for (int d = 1; d < 64; d <<= 1) s += __shfl_xor(s, d);
      if (lane == 0) {
        float t = s + fc1_b[o];
        h1[o] = LEAKY(t);
      }
    }
  }
  __syncthreads();
  {  // fc2: 16 waves x 16 outputs
    const float4* h1v = (const float4*)h1;
    float4 u0 = h1v[lane], u1 = h1v[64 + lane];
#pragma unroll 2
    for (int pass = 0; pass < 16; pass++) {
      int o = w * 16 + pass;
      const float4* wr = (const float4*)(fc2_w + (size_t)o * 512);
      float4 w0 = wr[lane], w1 = wr[64 + lane];
      float sa = fmaf(w0.x, u0.x, 0.f), sb = fmaf(w0.y, u0.y, 0.f);
      float sc = fmaf(w0.z, u0.z, 0.f), sd = fmaf(w0.w, u0.w, 0.f);
      sa = fmaf(w1.x, u1.x, sa); sb = fmaf(w1.y, u1.y, sb);
      sc = fmaf(w1.z, u1.z, sc); sd = fmaf(w1.w, u1.w, sd);
      float s = (sa + sb) + (sc + sd);
#pragma unroll
      for (int d = 1; d < 64; d <<= 1) s += __shfl_xor(s, d);
      if (lane == 0) {
        float t = s + fc2_b[o];
        h2[o] = LEAKY(t);
      }
    }
  }
  __syncthreads();
  if (w < 7) {  // heads: wave-per-output
    bool isrot = w < 4;
    int o = isrot ? w : w - 4;
    const float4* wr = (const float4*)((isrot ? fcr_w : fct_w) + (size_t)o * 256);
    const float4* uv = (const float4*)h2;
    float4 wv = wr[lane];
    float4 u = uv[lane];
    float s = fmaf(wv.x, u.x, fmaf(wv.y, u.y, fmaf(wv.z, u.z, wv.w * u.w)));
#pragma unroll
    for (int d = 1; d < 64; d <<= 1) s += __shfl_xor(s, d);
    if (lane == 0) {
      float t = s + (isrot ? fcr_b[o] : fct_b[o]);
      out[isrot ? (b * 4 + o) : (128 + b * 3 + o)] = t;
    }
  }
}

extern "C" void kernel_launch(void* const* d_in, const int* in_sizes, int n_in,
                              void* d_out, int out_size, void* d_ws, size_t ws_size,
                              hipStream_t stream) {
  const float* coor    = (const float*)d_in[0];
  const float* region  = (const float*)d_in[1];
  const float* extents = (const float*)d_in[2];
  const float* w1 = (const float*)d_in[3];  const float* b1 = (const float*)d_in[4];
  const float* w2 = (const float*)d_in[5];  const float* b2 = (const float*)d_in[6];
  const float* w3 = (const float*)d_in[7];  const float* b3 = (const float*)d_in[8];
  const float* w_sp = (const float*)d_in[9];  const float* b_sp = (const float*)d_in[10];
  const float* fc1_w = (const float*)d_in[11]; const float* fc1_b = (const float*)d_in[12];
  const float* fc2_w = (const float*)d_in[13]; const float* fc2_b = (const float*)d_in[14];
  const float* fcr_w = (const float*)d_in[15]; const float* fcr_b = (const float*)d_in[16];
  const float* fct_w = (const float*)d_in[17]; const float* fct_b = (const float*)d_in[18];

  char* ws = (char*)d_ws;
  unsigned* pool = (unsigned*)(ws + OFF_POOL);
  unsigned short* wsp = (unsigned short*)(ws + OFF_WSP);
  float* y32  = (float*)(ws + OFF_Y32);
  float* out  = (float*)d_out;

  kW<<<dim3(128), 256, 0, stream>>>(w2, w3, wsp, pool);
  kA<<<dim3(NTILES, NBATCH), 256, 0, stream>>>(coor, region, extents,
                                               w1, b1, b2, b3, wsp, pool);
  kC<<<dim3(32, 8), 256, 0, stream>>>(pool, w_sp, y32);
  kE<<<dim3(NBATCH), 1024, 0, stream>>>(y32, b_sp, fc1_w, fc1_b, fc2_w, fc2_b,
                                        fcr_w, fcr_b, fct_w, fct_b, out);
}

// Round 10
// 158.614 us; speedup vs baseline: 1.3284x; 1.3284x over previous
//
#include <hip/hip_runtime.h>
#include <cstddef>
#include <cstdint>

#define LEAKY(s) ((s) >= 0.f ? (s) : 0.1f * (s))

constexpr int PTS    = 4096;   // H*W
constexpr int NBATCH = 32;
constexpr int NM     = 8;      // regions
constexpr int TILE   = 128;    // points per block in kA
constexpr int NTILES = PTS / TILE;  // 32

// ---------------- workspace layout (bytes) ----------------
constexpr size_t OFF_POOL = 0;        // pool (B,1024) u32 (enc f32) 128KB
constexpr size_t OFF_WSP  = 131072;   // split weights w2h/w2l/w3h/w3l 128KB
constexpr size_t OFF_Y64  = 262144;   // y64 (B,64,1024) f32 8MB

using bf16x8 = __attribute__((ext_vector_type(8))) short;
using f32x4v = __attribute__((ext_vector_type(4))) float;
using u16x4  = __attribute__((ext_vector_type(4))) unsigned short;
using u16x8  = __attribute__((ext_vector_type(8))) unsigned short;

// split f32 -> bf16 hi (truncate) + bf16 lo (RNE of remainder): x ~ hi + lo
__device__ __forceinline__ void splitbf(float x, unsigned short& h, unsigned short& l) {
  unsigned u = __float_as_uint(x);
  unsigned short hh = (unsigned short)(u >> 16);
  float r = x - __uint_as_float((unsigned)hh << 16);
  unsigned v = __float_as_uint(r);
  unsigned rr = (v + 0x7FFFu + ((v >> 16) & 1u)) >> 16;
  h = hh; l = (unsigned short)rr;
}

// monotone f32 <-> u32 encoding (order-preserving) for atomicMax pooling
__device__ __forceinline__ unsigned encf(float f) {
  unsigned u = __float_as_uint(f);
  return (u & 0x80000000u) ? ~u : (u | 0x80000000u);
}
__device__ __forceinline__ float decf(unsigned e) {
  unsigned u = (e & 0x80000000u) ? (e ^ 0x80000000u) : ~e;
  return __uint_as_float(u);
}

// swizzled byte offset into Xt[pt][k] bf16 arrays (row = 256B): XOR bits 4..6 by pt&7
__device__ __forceinline__ int swzb(int pt, int kByte) {
  return pt * 256 + (kByte ^ ((pt & 7) << 4));
}

// ============================================================
// Kernel W: pre-split w2/w3 into bf16 hi/lo planes in A-fragment order
// AND zero the pool. grid(128),256.
// elem = (((mt*4+kt)*4+l4)*16+l15)*8+e ; c=mt*16+l15, k=kt*32+l4*8+e
// ============================================================
__global__ __launch_bounds__(256) void kW(const float* __restrict__ w2,
                                          const float* __restrict__ w3,
                                          unsigned short* __restrict__ wsp,
                                          unsigned* __restrict__ pool) {
  int id = blockIdx.x * 256 + threadIdx.x;   // 0..32767
  pool[id] = 0u;                             // enc(x) > 0 for all finite x
  int layer = id >> 14, e16 = id & 16383;
  int e = e16 & 7, l15 = (e16 >> 3) & 15, l4 = (e16 >> 7) & 3,
      kt = (e16 >> 9) & 3, mt = e16 >> 11;
  int c = mt * 16 + l15, k = kt * 32 + l4 * 8 + e;
  float v = (layer ? w3 : w2)[c * 128 + k];
  unsigned short h, l;
  splitbf(v, h, l);
  wsp[layer * 32768 + e16] = h;
  wsp[layer * 32768 + 16384 + e16] = l;
}

// ============================================================
// Kernel A (R8 winner, channel-split waves): conv1 -> conv2 -> conv3
// (split-bf16 MFMA) -> masked-max -> atomicMax pool.
// grid (NTILES=32, B), 256 thr, 2 blocks/CU.
// ============================================================
__device__ __forceinline__ void mfmaLayer(const unsigned short* __restrict__ Wh,
                                          const unsigned short* __restrict__ Wl,
                                          const float* __restrict__ bias,
                                          const char* XHc, const char* XLc,
                                          int lane, int mt0, f32x4v acc[2][8]) {
  const int l15 = lane & 15, l4 = lane >> 4;
#pragma unroll
  for (int mi = 0; mi < 2; mi++) {
    float4 bv = *(const float4*)(bias + (mt0 + mi) * 16 + l4 * 4);
    f32x4v b4; b4[0] = bv.x; b4[1] = bv.y; b4[2] = bv.z; b4[3] = bv.w;
#pragma unroll
    for (int nt = 0; nt < 8; nt++) acc[mi][nt] = b4;
  }
#pragma unroll
  for (int kt = 0; kt < 4; kt++) {
    bf16x8 ah[2], al[2];
#pragma unroll
    for (int mi = 0; mi < 2; mi++) {
      int off = ((((mt0 + mi) * 4 + kt) * 4 + l4) * 16 + l15) * 8;
      ah[mi] = *(const bf16x8*)(Wh + off);
      al[mi] = *(const bf16x8*)(Wl + off);
    }
    const int kb = (kt * 32 + l4 * 8) * 2;
#pragma unroll
    for (int nt = 0; nt < 8; nt++) {
      const int off = swzb(nt * 16 + l15, kb);
      bf16x8 bh = *(const bf16x8*)(XHc + off);
      bf16x8 bl = *(const bf16x8*)(XLc + off);
#pragma unroll
      for (int mi = 0; mi < 2; mi++) {
        acc[mi][nt] = __builtin_amdgcn_mfma_f32_16x16x32_bf16(ah[mi], bh, acc[mi][nt], 0, 0, 0);
        acc[mi][nt] = __builtin_amdgcn_mfma_f32_16x16x32_bf16(ah[mi], bl, acc[mi][nt], 0, 0, 0);
        acc[mi][nt] = __builtin_amdgcn_mfma_f32_16x16x32_bf16(al[mi], bh, acc[mi][nt], 0, 0, 0);
      }
    }
  }
}

__global__ __launch_bounds__(256, 2) void kA(
    const float* __restrict__ coor, const float* __restrict__ region,
    const float* __restrict__ extents,
    const float* __restrict__ w1, const float* __restrict__ b1,
    const float* __restrict__ b2, const float* __restrict__ b3,
    const unsigned short* __restrict__ wsp,
    unsigned* __restrict__ pool) {
  __shared__ unsigned short XH[128 * 128];  // 32KB (f32 funnel aliases in epilogue)
  __shared__ unsigned short XL[128 * 128];  // 32KB
  __shared__ float reg_s[NM * TILE];        // 4KB
  const int tid = threadIdx.x;
  const int b = blockIdx.y;
  const int t0 = blockIdx.x * TILE;
  const int lane = tid & 63;
  const int wv = tid >> 6;
  char* XHc = (char*)XH;
  char* XLc = (char*)XL;

  {  // stage region tile: 8 rows x 128
    int m = tid >> 5, j = tid & 31;
    float4 v = *(const float4*)(region + ((size_t)b * NM + m) * PTS + t0 + j * 4);
    *(float4*)(reg_s + m * TILE + j * 4) = v;
  }
  {  // layer 1 (K=5): thread = (pt, ch-half); writes Xt bf16 hi/lo
    const int pt = tid & 127;
    const int chh = (tid >> 7) * 64;
    float e0 = extents[b * 3], e1 = extents[b * 3 + 1], e2 = extents[b * 3 + 2];
    float in5[5];
#pragma unroll
    for (int i = 0; i < 5; i++) in5[i] = coor[((size_t)b * 5 + i) * PTS + t0 + pt];
    in5[0] = (in5[0] - 0.5f) * e0;
    in5[1] = (in5[1] - 0.5f) * e1;
    in5[2] = (in5[2] - 0.5f) * e2;
    for (int c8 = 0; c8 < 64; c8 += 8) {
      u16x8 hh, ll;
#pragma unroll
      for (int q = 0; q < 8; q++) {
        int c = chh + c8 + q;
        float s = b1[c];
#pragma unroll
        for (int i = 0; i < 5; i++) s = fmaf(w1[c * 5 + i], in5[i], s);
        s = LEAKY(s);
        unsigned short h, l;
        splitbf(s, h, l);
        hh[q] = h; ll[q] = l;
      }
      int off = swzb(pt, (chh + c8) * 2);
      *(u16x8*)(XHc + off) = hh;
      *(u16x8*)(XLc + off) = ll;
    }
  }
  __syncthreads();

  f32x4v acc[2][8];
  const int mt0 = wv * 2;
  const int l15 = lane & 15, l4 = lane >> 4;

  // layer 2
  mfmaLayer(wsp, wsp + 16384, b2, XHc, XLc, lane, mt0, acc);
  __syncthreads();
  {  // leaky + split + write act2 back to Xt
#pragma unroll
    for (int mi = 0; mi < 2; mi++) {
      const int ch0 = (mt0 + mi) * 16 + l4 * 4;
#pragma unroll
      for (int nt = 0; nt < 8; nt++) {
        u16x4 h4, l4v;
#pragma unroll
        for (int r = 0; r < 4; r++) {
          float s = acc[mi][nt][r];
          s = LEAKY(s);
          unsigned short h, l;
          splitbf(s, h, l);
          h4[r] = h; l4v[r] = l;
        }
        int off = swzb(nt * 16 + l15, ch0 * 2);
        *(u16x4*)(XHc + off) = h4;
        *(u16x4*)(XLc + off) = l4v;
      }
    }
  }
  __syncthreads();
  // layer 3 (bias, no activation)
  mfmaLayer(wsp + 32768, wsp + 49152, b3, XHc, XLc, lane, mt0, acc);
  __syncthreads();  // all reads done; reuse XH as f32 funnel

  {  // region-masked max -> funnel[c*8+m]
    float* funnel = (float*)XH;
#pragma unroll
    for (int m = 0; m < NM; m++) {
      float rv[8];
#pragma unroll
      for (int nt = 0; nt < 8; nt++) rv[nt] = reg_s[m * TILE + nt * 16 + l15];
#pragma unroll
      for (int mi = 0; mi < 2; mi++)
#pragma unroll
        for (int r = 0; r < 4; r++) {
          float mx = acc[mi][0][r] * rv[0];
#pragma unroll
          for (int nt = 1; nt < 8; nt++) mx = fmaxf(mx, acc[mi][nt][r] * rv[nt]);
          mx = fmaxf(mx, __shfl_xor(mx, 1));
          mx = fmaxf(mx, __shfl_xor(mx, 2));
          mx = fmaxf(mx, __shfl_xor(mx, 4));
          mx = fmaxf(mx, __shfl_xor(mx, 8));
          if (l15 == 0) funnel[((mt0 + mi) * 16 + l4 * 4 + r) * 8 + m] = mx;
        }
    }
  }
  __syncthreads();
  {  // order-independent pool: atomicMax of monotone-encoded f32
    const float* fun = (const float*)XH;
    float4 v = *(const float4*)(fun + tid * 4);
    unsigned* pl = pool + (size_t)b * 1024 + tid * 4;
    atomicMax(pl + 0, encf(v.x));
    atomicMax(pl + 1, encf(v.y));
    atomicMax(pl + 2, encf(v.z));
    atomicMax(pl + 3, encf(v.w));
  }
}

// ============================================================
// Kernel C (k-split, 2 blocks/CU): decode pool -> softmax -> per-k sort ->
// GEMM D[b,k,m,o] = sum_c xs[c,m]*w_sp[o,c,k] -> fused gather-sum -> y64.
// grid (64 ktiles of 2, 8 bgroups of 4), 256 thr. As stride 276:
// staging writes ~2-way banks, compute reads 16B-aligned conflict-free.
// T14 prefetch: next c0 chunk's global loads issued before compute.
// ============================================================
__global__ __launch_bounds__(256) void kC(const unsigned* __restrict__ pool,
                                          const float* __restrict__ w_sp,
                                          float* __restrict__ y64) {
  __shared__ float As[16 * 276];     // 17.7KB  [cc][row=kk*128+o]
  __shared__ float xsl[4 * 128 * 8]; // 16KB    [bl][c][m]
  __shared__ int idxL[4][2][8];      // [bl][kk][r]
  const int tid = threadIdx.x;
  const int k0 = blockIdx.x * 2;
  const int bbase = blockIdx.y * 4;
  const int rg = tid & 63, cgq = tid >> 6;

  // decode pool (4 b x 1024) -> xsl
#pragma unroll
  for (int it = 0; it < 4; it++) {
    uint4 v = *(const uint4*)(pool + (size_t)(bbase + it) * 1024 + tid * 4);
    float4 f = {decf(v.x), decf(v.y), decf(v.z), decf(v.w)};
    *(float4*)(xsl + it * 1024 + tid * 4) = f;
  }
  // prologue: issue c0=0 staging loads
  float2 wreg[8];
#pragma unroll
  for (int it = 0; it < 8; it++) {
    int q = tid + it * 256, o = q >> 4, cc = q & 15;
    wreg[it] = *(const float2*)(w_sp + (size_t)o * 16384 + (size_t)cc * 128 + k0);
  }
  __syncthreads();
  {  // softmax over c per (bl, m): 32 pairs x 8 threads
    int pair = tid >> 3, sub = tid & 7;
    int bl = pair >> 3, m = pair & 7;
    float* base = xsl + bl * 1024 + m;
    float v[16];
#pragma unroll
    for (int j = 0; j < 16; j++) v[j] = base[(sub + 8 * j) * 8];
    float mx = v[0];
#pragma unroll
    for (int j = 1; j < 16; j++) mx = fmaxf(mx, v[j]);
    mx = fmaxf(mx, __shfl_xor(mx, 1));
    mx = fmaxf(mx, __shfl_xor(mx, 2));
    mx = fmaxf(mx, __shfl_xor(mx, 4));
    float s = 0.f;
#pragma unroll
    for (int j = 0; j < 16; j++) { v[j] = expf(v[j] - mx); s += v[j]; }
    s += __shfl_xor(s, 1);
    s += __shfl_xor(s, 2);
    s += __shfl_xor(s, 4);
    float inv = 1.f / s;
#pragma unroll
    for (int j = 0; j < 16; j++) base[(sub + 8 * j) * 8] = v[j] * inv;
  }
  __syncthreads();
  if (tid < 8) {  // sort this block's 2 k-channels per batch
    int bl = tid >> 1, kk = tid & 1;
    float vv[8];
#pragma unroll
    for (int n = 0; n < 8; n++) vv[n] = xsl[bl * 1024 + (k0 + kk) * 8 + n];
    int used = 0;
#pragma unroll
    for (int n = 0; n < 8; n++) {
      int best = 0; float bv = -1.f;
#pragma unroll
      for (int q = 0; q < 8; q++) {
        bool ok = ((used >> q) & 1) == 0;
        if (ok && vv[q] > bv) { bv = vv[q]; best = q; }  // strict > == lowest-index tie-break
      }
      used |= 1 << best;
      idxL[bl][kk][n] = best;
    }
  }

  float acc[4][8];
#pragma unroll
  for (int i = 0; i < 4; i++)
#pragma unroll
    for (int j = 0; j < 8; j++) acc[i][j] = 0.f;

  for (int c0 = 0; c0 < 128; c0 += 16) {
    __syncthreads();  // As free (consumed by previous compute)
#pragma unroll
    for (int it = 0; it < 8; it++) {
      int q = tid + it * 256, o = q >> 4, cc = q & 15;
      As[cc * 276 + o]       = wreg[it].x;
      As[cc * 276 + 128 + o] = wreg[it].y;
    }
    __syncthreads();
    if (c0 + 16 < 128) {  // issue next chunk early (hidden under compute)
#pragma unroll
      for (int it = 0; it < 8; it++) {
        int q = tid + it * 256, o = q >> 4, cc = q & 15;
        wreg[it] = *(const float2*)(w_sp + (size_t)o * 16384 + (size_t)(c0 + 16 + cc) * 128 + k0);
      }
    }
#pragma unroll
    for (int cc = 0; cc < 16; cc++) {
      float4 a = *(const float4*)(As + cc * 276 + rg * 4);
      float4 p0 = *(const float4*)(xsl + cgq * 1024 + (c0 + cc) * 8);      // broadcast
      float4 p1 = *(const float4*)(xsl + cgq * 1024 + (c0 + cc) * 8 + 4);  // broadcast
      float av[4] = {a.x, a.y, a.z, a.w};
      float bv[8] = {p0.x, p0.y, p0.z, p0.w, p1.x, p1.y, p1.z, p1.w};
#pragma unroll
      for (int i = 0; i < 4; i++)
#pragma unroll
        for (int j = 0; j < 8; j++) acc[i][j] = fmaf(av[i], bv[j], acc[i][j]);
    }
  }
  // gather-sum epilogue: row = rg*4+i -> kk = rg>>5, o = row & 127; col j -> m.
  // wave cgq owns batch bbase+cgq. shfl_xor(32) folds the 2 kk halves.
  const int kk = rg >> 5;
  int ms[8];
#pragma unroll
  for (int r = 0; r < 8; r++) ms[r] = idxL[cgq][kk][r];
  float yp[4][8];
#pragma unroll
  for (int i4 = 0; i4 < 4; i4++) {
#pragma unroll
    for (int r = 0; r < 8; r++) {
      float v = 0.f;
#pragma unroll
      for (int j = 0; j < 8; j++) v += (j == ms[r]) ? acc[i4][j] : 0.f;
      yp[i4][r] = v;
    }
  }
#pragma unroll
  for (int i4 = 0; i4 < 4; i4++)
#pragma unroll
    for (int r = 0; r < 8; r++) yp[i4][r] += __shfl_xor(yp[i4][r], 32);
  if (rg < 32) {  // lane rg holds o = rg*4+i4, summed over both kk
    float* dst = y64 + ((size_t)(bbase + cgq) * 64 + blockIdx.x) * 1024 + rg * 32;
#pragma unroll
    for (int i4 = 0; i4 < 4; i4++) {
      float4 v0 = {yp[i4][0], yp[i4][1], yp[i4][2], yp[i4][3]};
      float4 v1 = {yp[i4][4], yp[i4][5], yp[i4][6], yp[i4][7]};
      *(float4*)(dst + i4 * 8) = v0;
      *(float4*)(dst + i4 * 8 + 4) = v1;
    }
  }
}

// ============================================================
// Kernel E: assemble y (sum 64 tiles + b_sp + leaky) -> fc1 -> fc2 -> heads.
// grid (B), 1024 thr (16 waves).
// ============================================================
__global__ __launch_bounds__(1024) void kE(
    const float* __restrict__ y64, const float* __restrict__ b_sp,
    const float* __restrict__ fc1_w, const float* __restrict__ fc1_b,
    const float* __restrict__ fc2_w, const float* __restrict__ fc2_b,
    const float* __restrict__ fcr_w, const float* __restrict__ fcr_b,
    const float* __restrict__ fct_w, const float* __restrict__ fct_b,
    float* __restrict__ out) {
  __shared__ float yl[1024];
  __shared__ float h1[512];
  __shared__ float h2[256];
  int b = blockIdx.x, tid = threadIdx.x;
  int w = tid >> 6, lane = tid & 63;
  {  // assemble y: thread per feature
    const float* base = y64 + (size_t)b * 65536 + tid;
    float s = 0.f;
#pragma unroll 8
    for (int t = 0; t < 64; t++) s += base[t * 1024];
    s += b_sp[tid >> 3];
    yl[tid] = LEAKY(s);
  }
  __syncthreads();
  {  // fc1: 16 waves x 32 outputs
    const float4* ylv = (const float4*)yl;
    float4 u[4];
#pragma unroll
    for (int r = 0; r < 4; r++) u[r] = ylv[r * 64 + lane];
#pragma unroll 2
    for (int pass = 0; pass < 32; pass++) {
      int o = w * 32 + pass;
      const float4* wr = (const float4*)(fc1_w + (size_t)o * 1024);
      float sa = 0, sb = 0, sc = 0, sd = 0;
#pragma unroll
      for (int r = 0; r < 4; r++) {
        float4 wv = wr[r * 64 + lane];
        sa = fmaf(wv.x, u[r].x, sa); sb = fmaf(wv.y, u[r].y, sb);
        sc = fmaf(wv.z, u[r].z, sc); sd = fmaf(wv.w, u[r].w, sd);
      }
      float s = (sa + sb) + (sc + sd);
#pragma unroll
      for (int d = 1; d < 64; d <<= 1) s += __shfl_xor(s, d);
      if (lane == 0) {
        float t = s + fc1_b[o];
        h1[o] = LEAKY(t);
      }
    }
  }
  __syncthreads();
  {  // fc2: 16 waves x 16 outputs
    const float4* h1v = (const float4*)h1;
    float4 u0 = h1v[lane], u1 = h1v[64 + lane];
#pragma unroll 2
    for (int pass = 0; pass < 16; pass++) {
      int o = w * 16 + pass;
      const float4* wr = (const float4*)(fc2_w + (size_t)o * 512);
      float4 w0 = wr[lane], w1 = wr[64 + lane];
      float sa = fmaf(w0.x, u0.x, 0.f), sb = fmaf(w0.y, u0.y, 0.f);
      float sc = fmaf(w0.z, u0.z, 0.f), sd = fmaf(w0.w, u0.w, 0.f);
      sa = fmaf(w1.x, u1.x, sa); sb = fmaf(w1.y, u1.y, sb);
      sc = fmaf(w1.z, u1.z, sc); sd = fmaf(w1.w, u1.w, sd);
      float s = (sa + sb) + (sc + sd);
#pragma unroll
      for (int d = 1; d < 64; d <<= 1) s += __shfl_xor(s, d);
      if (lane == 0) {
        float t = s + fc2_b[o];
        h2[o] = LEAKY(t);
      }
    }
  }
  __syncthreads();
  if (w < 7) {  // heads: wave-per-output
    bool isrot = w < 4;
    int o = isrot ? w : w - 4;
    const float4* wr = (const float4*)((isrot ? fcr_w : fct_w) + (size_t)o * 256);
    const float4* uv = (const float4*)h2;
    float4 wv = wr[lane];
    float4 u = uv[lane];
    float s = fmaf(wv.x, u.x, fmaf(wv.y, u.y, fmaf(wv.z, u.z, wv.w * u.w)));
#pragma unroll
    for (int d = 1; d < 64; d <<= 1) s += __shfl_xor(s, d);
    if (lane == 0) {
      float t = s + (isrot ? fcr_b[o] : fct_b[o]);
      out[isrot ? (b * 4 + o) : (128 + b * 3 + o)] = t;
    }
  }
}

extern "C" void kernel_launch(void* const* d_in, const int* in_sizes, int n_in,
                              void* d_out, int out_size, void* d_ws, size_t ws_size,
                              hipStream_t stream) {
  const float* coor    = (const float*)d_in[0];
  const float* region  = (const float*)d_in[1];
  const float* extents = (const float*)d_in[2];
  const float* w1 = (const float*)d_in[3];  const float* b1 = (const float*)d_in[4];
  const float* w2 = (const float*)d_in[5];  const float* b2 = (const float*)d_in[6];
  const float* w3 = (const float*)d_in[7];  const float* b3 = (const float*)d_in[8];
  const float* w_sp = (const float*)d_in[9];  const float* b_sp = (const float*)d_in[10];
  const float* fc1_w = (const float*)d_in[11]; const float* fc1_b = (const float*)d_in[12];
  const float* fc2_w = (const float*)d_in[13]; const float* fc2_b = (const float*)d_in[14];
  const float* fcr_w = (const float*)d_in[15]; const float* fcr_b = (const float*)d_in[16];
  const float* fct_w = (const float*)d_in[17]; const float* fct_b = (const float*)d_in[18];

  char* ws = (char*)d_ws;
  unsigned* pool = (unsigned*)(ws + OFF_POOL);
  unsigned short* wsp = (unsigned short*)(ws + OFF_WSP);
  float* y64  = (float*)(ws + OFF_Y64);
  float* out  = (float*)d_out;

  kW<<<dim3(128), 256, 0, stream>>>(w2, w3, wsp, pool);
  kA<<<dim3(NTILES, NBATCH), 256, 0, stream>>>(coor, region, extents,
                                               w1, b1, b2, b3, wsp, pool);
  kC<<<dim3(64, 8), 256, 0, stream>>>(pool, w_sp, y64);
  kE<<<dim3(NBATCH), 1024, 0, stream>>>(y64, b_sp, fc1_w, fc1_b, fc2_w, fc2_b,
                                        fcr_w, fcr_b, fct_w, fct_b, out);
}

// Round 11
// 130.352 us; speedup vs baseline: 1.6164x; 1.2168x over previous
//
#include <hip/hip_runtime.h>
#include <cstddef>
#include <cstdint>

#define LEAKY(s) ((s) >= 0.f ? (s) : 0.1f * (s))

constexpr int PTS    = 4096;   // H*W
constexpr int NBATCH = 32;
constexpr int NM     = 8;      // regions
constexpr int TILE   = 128;    // points per block in kA
constexpr int NTILES = PTS / TILE;  // 32

// ---------------- workspace layout (bytes) ----------------
constexpr size_t OFF_POOL = 0;        // pool (B,1024) u32 (enc f32) 128KB
constexpr size_t OFF_WSP  = 131072;   // split weights w2h/w2l/w3h/w3l 128KB
constexpr size_t OFF_Y32  = 262144;   // y32 (B,32,1024) f32 4MB

using bf16x8 = __attribute__((ext_vector_type(8))) short;
using f32x4v = __attribute__((ext_vector_type(4))) float;
using u16x4  = __attribute__((ext_vector_type(4))) unsigned short;
using u16x8  = __attribute__((ext_vector_type(8))) unsigned short;

// split f32 -> bf16 hi (truncate) + bf16 lo (RNE of remainder): x ~ hi + lo
__device__ __forceinline__ void splitbf(float x, unsigned short& h, unsigned short& l) {
  unsigned u = __float_as_uint(x);
  unsigned short hh = (unsigned short)(u >> 16);
  float r = x - __uint_as_float((unsigned)hh << 16);
  unsigned v = __float_as_uint(r);
  unsigned rr = (v + 0x7FFFu + ((v >> 16) & 1u)) >> 16;
  h = hh; l = (unsigned short)rr;
}

// monotone f32 <-> u32 encoding (order-preserving) for atomicMax pooling
__device__ __forceinline__ unsigned encf(float f) {
  unsigned u = __float_as_uint(f);
  return (u & 0x80000000u) ? ~u : (u | 0x80000000u);
}
__device__ __forceinline__ float decf(unsigned e) {
  unsigned u = (e & 0x80000000u) ? (e ^ 0x80000000u) : ~e;
  return __uint_as_float(u);
}

// swizzled byte offset into Xt[pt][k] bf16 arrays (row = 256B): XOR bits 4..6 by pt&7
__device__ __forceinline__ int swzb(int pt, int kByte) {
  return pt * 256 + (kByte ^ ((pt & 7) << 4));
}

// ============================================================
// Kernel W: pre-split w2/w3 into bf16 hi/lo planes in A-fragment order
// AND zero the pool. grid(128),256.
// elem = (((mt*4+kt)*4+l4)*16+l15)*8+e ; c=mt*16+l15, k=kt*32+l4*8+e
// ============================================================
__global__ __launch_bounds__(256) void kW(const float* __restrict__ w2,
                                          const float* __restrict__ w3,
                                          unsigned short* __restrict__ wsp,
                                          unsigned* __restrict__ pool) {
  int id = blockIdx.x * 256 + threadIdx.x;   // 0..32767
  pool[id] = 0u;                             // enc(x) > 0 for all finite x
  int layer = id >> 14, e16 = id & 16383;
  int e = e16 & 7, l15 = (e16 >> 3) & 15, l4 = (e16 >> 7) & 3,
      kt = (e16 >> 9) & 3, mt = e16 >> 11;
  int c = mt * 16 + l15, k = kt * 32 + l4 * 8 + e;
  float v = (layer ? w3 : w2)[c * 128 + k];
  unsigned short h, l;
  splitbf(v, h, l);
  wsp[layer * 32768 + e16] = h;
  wsp[layer * 32768 + 16384 + e16] = l;
}

// ============================================================
// Kernel A: conv1 -> conv2 -> conv3 (split-bf16 MFMA) -> masked-max ->
// atomicMax pool. grid (NTILES=32, B), **512 thr / 8 waves**, 2 blocks/CU
// -> 16 waves/CU (4/SIMD) for 2x latency hiding at the same LDS footprint.
// Wave wv owns m-tile mt=wv (16 out-channels) x all 128 points.
// ============================================================
__device__ __forceinline__ void mfmaLayer8(const unsigned short* __restrict__ Wh,
                                           const unsigned short* __restrict__ Wl,
                                           const float* __restrict__ bias,
                                           const char* XHc, const char* XLc,
                                           int lane, int mt, f32x4v acc[8]) {
  const int l15 = lane & 15, l4 = lane >> 4;
  {
    float4 bv = *(const float4*)(bias + mt * 16 + l4 * 4);
    f32x4v b4; b4[0] = bv.x; b4[1] = bv.y; b4[2] = bv.z; b4[3] = bv.w;
#pragma unroll
    for (int nt = 0; nt < 8; nt++) acc[nt] = b4;
  }
#pragma unroll
  for (int kt = 0; kt < 4; kt++) {
    int woff = (((mt * 4 + kt) * 4 + l4) * 16 + l15) * 8;
    bf16x8 ah = *(const bf16x8*)(Wh + woff);
    bf16x8 al = *(const bf16x8*)(Wl + woff);
    const int kb = (kt * 32 + l4 * 8) * 2;
#pragma unroll
    for (int nt = 0; nt < 8; nt++) {
      const int off = swzb(nt * 16 + l15, kb);
      bf16x8 bh = *(const bf16x8*)(XHc + off);
      bf16x8 bl = *(const bf16x8*)(XLc + off);
      acc[nt] = __builtin_amdgcn_mfma_f32_16x16x32_bf16(ah, bh, acc[nt], 0, 0, 0);
      acc[nt] = __builtin_amdgcn_mfma_f32_16x16x32_bf16(ah, bl, acc[nt], 0, 0, 0);
      acc[nt] = __builtin_amdgcn_mfma_f32_16x16x32_bf16(al, bh, acc[nt], 0, 0, 0);
    }
  }
}

__global__ __launch_bounds__(512, 2) void kA(
    const float* __restrict__ coor, const float* __restrict__ region,
    const float* __restrict__ extents,
    const float* __restrict__ w1, const float* __restrict__ b1,
    const float* __restrict__ b2, const float* __restrict__ b3,
    const unsigned short* __restrict__ wsp,
    unsigned* __restrict__ pool) {
  __shared__ unsigned short XH[128 * 128];  // 32KB (f32 funnel aliases in epilogue)
  __shared__ unsigned short XL[128 * 128];  // 32KB
  __shared__ float reg_s[NM * TILE];        // 4KB
  const int tid = threadIdx.x;
  const int b = blockIdx.y;
  const int t0 = blockIdx.x * TILE;
  const int lane = tid & 63;
  const int wv = tid >> 6;                  // 0..7
  char* XHc = (char*)XH;
  char* XLc = (char*)XL;

  {  // stage region tile: 8 rows x 128 (float2/thread)
    int m = tid >> 6, j = tid & 63;
    float2 v = *(const float2*)(region + ((size_t)b * NM + m) * PTS + t0 + j * 2);
    *(float2*)(reg_s + m * TILE + j * 2) = v;
  }
  {  // layer 1 (K=5): thread = (pt, ch-quarter); writes Xt bf16 hi/lo
    const int pt = tid & 127;
    const int chq = (tid >> 7) * 32;
    float e0 = extents[b * 3], e1 = extents[b * 3 + 1], e2 = extents[b * 3 + 2];
    float in5[5];
#pragma unroll
    for (int i = 0; i < 5; i++) in5[i] = coor[((size_t)b * 5 + i) * PTS + t0 + pt];
    in5[0] = (in5[0] - 0.5f) * e0;
    in5[1] = (in5[1] - 0.5f) * e1;
    in5[2] = (in5[2] - 0.5f) * e2;
#pragma unroll
    for (int c8 = 0; c8 < 32; c8 += 8) {
      u16x8 hh, ll;
#pragma unroll
      for (int q = 0; q < 8; q++) {
        int c = chq + c8 + q;
        float s = b1[c];
#pragma unroll
        for (int i = 0; i < 5; i++) s = fmaf(w1[c * 5 + i], in5[i], s);
        s = LEAKY(s);
        unsigned short h, l;
        splitbf(s, h, l);
        hh[q] = h; ll[q] = l;
      }
      int off = swzb(pt, (chq + c8) * 2);
      *(u16x8*)(XHc + off) = hh;
      *(u16x8*)(XLc + off) = ll;
    }
  }
  __syncthreads();

  f32x4v acc[8];
  const int mt = wv;
  const int l15 = lane & 15, l4 = lane >> 4;

  // layer 2
  mfmaLayer8(wsp, wsp + 16384, b2, XHc, XLc, lane, mt, acc);
  __syncthreads();
  {  // leaky + split + write act2 back to Xt (ch0 = mt*16 + l4*4, pts nt*16+l15)
    const int ch0 = mt * 16 + l4 * 4;
#pragma unroll
    for (int nt = 0; nt < 8; nt++) {
      u16x4 h4, l4v;
#pragma unroll
      for (int r = 0; r < 4; r++) {
        float s = acc[nt][r];
        s = LEAKY(s);
        unsigned short h, l;
        splitbf(s, h, l);
        h4[r] = h; l4v[r] = l;
      }
      int off = swzb(nt * 16 + l15, ch0 * 2);
      *(u16x4*)(XHc + off) = h4;
      *(u16x4*)(XLc + off) = l4v;
    }
  }
  __syncthreads();
  // layer 3 (bias, no activation)
  mfmaLayer8(wsp + 32768, wsp + 49152, b3, XHc, XLc, lane, mt, acc);
  __syncthreads();  // all reads done; reuse XH as f32 funnel

  {  // region-masked max -> funnel[c*8+m]
    float* funnel = (float*)XH;
#pragma unroll
    for (int m = 0; m < NM; m++) {
      float rv[8];
#pragma unroll
      for (int nt = 0; nt < 8; nt++) rv[nt] = reg_s[m * TILE + nt * 16 + l15];
#pragma unroll
      for (int r = 0; r < 4; r++) {
        float mx = acc[0][r] * rv[0];
#pragma unroll
        for (int nt = 1; nt < 8; nt++) mx = fmaxf(mx, acc[nt][r] * rv[nt]);
        mx = fmaxf(mx, __shfl_xor(mx, 1));
        mx = fmaxf(mx, __shfl_xor(mx, 2));
        mx = fmaxf(mx, __shfl_xor(mx, 4));
        mx = fmaxf(mx, __shfl_xor(mx, 8));
        if (l15 == 0) funnel[(mt * 16 + l4 * 4 + r) * 8 + m] = mx;
      }
    }
  }
  __syncthreads();
  {  // order-independent pool: atomicMax of monotone-encoded f32 (2/thread)
    const float* fun = (const float*)XH;
    unsigned* pl = pool + (size_t)b * 1024;
    atomicMax(pl + tid, encf(fun[tid]));
    atomicMax(pl + tid + 512, encf(fun[tid + 512]));
  }
}

// ============================================================
// Kernel C (R9/R8 best): decode pool -> softmax -> per-k sort ->
// GEMM D[b,k,m,o] = sum_c xs[c,m]*w_sp[o,c,k] -> fused gather-sum -> y32.
// grid (32 ktiles of 4, 8 bgroups of 4), 256 thr. As stride 516.
// T14 prefetch: next c0 chunk's global loads issued before compute.
// ============================================================
__global__ __launch_bounds__(256) void kC(const unsigned* __restrict__ pool,
                                          const float* __restrict__ w_sp,
                                          float* __restrict__ y32) {
  __shared__ float As[16 * 516];     // 33KB
  __shared__ float xsl[4 * 128 * 8]; // 16KB  [bl][c][m]
  __shared__ int idxL[4][4][8];      // [bl][kk][r]
  const int tid = threadIdx.x;
  const int k0 = blockIdx.x * 4;
  const int bbase = blockIdx.y * 4;
  const int rg = tid & 63, cgq = tid >> 6;

  // decode pool (4 b x 1024) -> xsl
#pragma unroll
  for (int it = 0; it < 4; it++) {
    uint4 v = *(const uint4*)(pool + (size_t)(bbase + it) * 1024 + tid * 4);
    float4 f = {decf(v.x), decf(v.y), decf(v.z), decf(v.w)};
    *(float4*)(xsl + it * 1024 + tid * 4) = f;
  }
  // prologue: issue c0=0 staging loads
  float4 wreg[8];
#pragma unroll
  for (int it = 0; it < 8; it++) {
    int q = tid + it * 256, o = q >> 4, cc = q & 15;
    wreg[it] = *(const float4*)(w_sp + (size_t)o * 16384 + (size_t)cc * 128 + k0);
  }
  __syncthreads();
  {  // softmax over c per (bl, m): 32 pairs x 8 threads
    int pair = tid >> 3, sub = tid & 7;
    int bl = pair >> 3, m = pair & 7;
    float* base = xsl + bl * 1024 + m;
    float v[16];
#pragma unroll
    for (int j = 0; j < 16; j++) v[j] = base[(sub + 8 * j) * 8];
    float mx = v[0];
#pragma unroll
    for (int j = 1; j < 16; j++) mx = fmaxf(mx, v[j]);
    mx = fmaxf(mx, __shfl_xor(mx, 1));
    mx = fmaxf(mx, __shfl_xor(mx, 2));
    mx = fmaxf(mx, __shfl_xor(mx, 4));
    float s = 0.f;
#pragma unroll
    for (int j = 0; j < 16; j++) { v[j] = expf(v[j] - mx); s += v[j]; }
    s += __shfl_xor(s, 1);
    s += __shfl_xor(s, 2);
    s += __shfl_xor(s, 4);
    float inv = 1.f / s;
#pragma unroll
    for (int j = 0; j < 16; j++) base[(sub + 8 * j) * 8] = v[j] * inv;
  }
  __syncthreads();
  if (tid < 16) {  // sort this block's 4 k-channels per batch
    int bl = tid >> 2, kk = tid & 3;
    float vv[8];
#pragma unroll
    for (int n = 0; n < 8; n++) vv[n] = xsl[bl * 1024 + (k0 + kk) * 8 + n];
    int used = 0;
#pragma unroll
    for (int n = 0; n < 8; n++) {
      int best = 0; float bv = -1.f;
#pragma unroll
      for (int q = 0; q < 8; q++) {
        bool ok = ((used >> q) & 1) == 0;
        if (ok && vv[q] > bv) { bv = vv[q]; best = q; }  // strict > == lowest-index tie-break
      }
      used |= 1 << best;
      idxL[bl][kk][n] = best;
    }
  }

  float acc[8][8];
#pragma unroll
  for (int i = 0; i < 8; i++)
#pragma unroll
    for (int j = 0; j < 8; j++) acc[i][j] = 0.f;

  for (int c0 = 0; c0 < 128; c0 += 16) {
    __syncthreads();  // As free (consumed by previous compute)
#pragma unroll
    for (int it = 0; it < 8; it++) {
      int q = tid + it * 256, o = q >> 4, cc = q & 15;
      As[cc * 516 + o]       = wreg[it].x;
      As[cc * 516 + 128 + o] = wreg[it].y;
      As[cc * 516 + 256 + o] = wreg[it].z;
      As[cc * 516 + 384 + o] = wreg[it].w;
    }
    __syncthreads();
    if (c0 + 16 < 128) {  // issue next chunk early (hidden under compute)
#pragma unroll
      for (int it = 0; it < 8; it++) {
        int q = tid + it * 256, o = q >> 4, cc = q & 15;
        wreg[it] = *(const float4*)(w_sp + (size_t)o * 16384 + (size_t)(c0 + 16 + cc) * 128 + k0);
      }
    }
#pragma unroll
    for (int cc = 0; cc < 16; cc++) {
      float4 a0 = *(const float4*)(As + cc * 516 + rg * 4);
      float4 a1 = *(const float4*)(As + cc * 516 + 256 + rg * 4);
      float4 p0 = *(const float4*)(xsl + cgq * 1024 + (c0 + cc) * 8);      // broadcast
      float4 p1 = *(const float4*)(xsl + cgq * 1024 + (c0 + cc) * 8 + 4);  // broadcast
      float av[8] = {a0.x, a0.y, a0.z, a0.w, a1.x, a1.y, a1.z, a1.w};
      float bv[8] = {p0.x, p0.y, p0.z, p0.w, p1.x, p1.y, p1.z, p1.w};
#pragma unroll
      for (int i = 0; i < 8; i++)
#pragma unroll
        for (int j = 0; j < 8; j++) acc[i][j] = fmaf(av[i], bv[j], acc[i][j]);
    }
  }
  // gather-sum epilogue. acc rows: i<4 -> row rg*4+i (kk=rg>>5, o=row&127);
  // i>=4 -> row 256+rg*4+(i-4) (kk=2+(rg>>5)). wave cgq owns batch bbase+cgq.
  const int rgl = rg & 31;
  const int kkA = rg >> 5;
  int msA[8], msB[8];
#pragma unroll
  for (int r = 0; r < 8; r++) {
    msA[r] = idxL[cgq][kkA][r];
    msB[r] = idxL[cgq][2 + kkA][r];
  }
  float yp[4][8];
#pragma unroll
  for (int i4 = 0; i4 < 4; i4++) {
#pragma unroll
    for (int r = 0; r < 8; r++) {
      float v = 0.f;
#pragma unroll
      for (int j = 0; j < 8; j++) {
        v += (j == msA[r]) ? acc[i4][j] : 0.f;
        v += (j == msB[r]) ? acc[i4 + 4][j] : 0.f;
      }
      yp[i4][r] = v;
    }
  }
#pragma unroll
  for (int i4 = 0; i4 < 4; i4++)
#pragma unroll
    for (int r = 0; r < 8; r++) yp[i4][r] += __shfl_xor(yp[i4][r], 32);
  if (rg < 32) {  // lane rg holds o = rg*4+i4, summed over 4 kk
    float* dst = y32 + ((size_t)(bbase + cgq) * 32 + blockIdx.x) * 1024 + rgl * 32;
#pragma unroll
    for (int i4 = 0; i4 < 4; i4++) {
      float4 v0 = {yp[i4][0], yp[i4][1], yp[i4][2], yp[i4][3]};
      float4 v1 = {yp[i4][4], yp[i4][5], yp[i4][6], yp[i4][7]};
      *(float4*)(dst + i4 * 8) = v0;
      *(float4*)(dst + i4 * 8 + 4) = v1;
    }
  }
}

// ============================================================
// Kernel E: assemble y (sum 32 tiles + b_sp + leaky) -> fc1 -> fc2 -> heads.
// grid (B), 1024 thr (16 waves).
// ============================================================
__global__ __launch_bounds__(1024) void kE(
    const float* __restrict__ y32, const float* __restrict__ b_sp,
    const float* __restrict__ fc1_w, const float* __restrict__ fc1_b,
    const float* __restrict__ fc2_w, const float* __restrict__ fc2_b,
    const float* __restrict__ fcr_w, const float* __restrict__ fcr_b,
    const float* __restrict__ fct_w, const float* __restrict__ fct_b,
    float* __restrict__ out) {
  __shared__ float yl[1024];
  __shared__ float h1[512];
  __shared__ float h2[256];
  int b = blockIdx.x, tid = threadIdx.x;
  int w = tid >> 6, lane = tid & 63;
  {  // assemble y: thread per feature
    const float* base = y32 + (size_t)b * 32768 + tid;
    float s = 0.f;
#pragma unroll 8
    for (int t = 0; t < 32; t++) s += base[t * 1024];
    s += b_sp[tid >> 3];
    yl[tid] = LEAKY(s);
  }
  __syncthreads();
  {  // fc1: 16 waves x 32 outputs
    const float4* ylv = (const float4*)yl;
    float4 u[4];
#pragma unroll
    for (int r = 0; r < 4; r++) u[r] = ylv[r * 64 + lane];
#pragma unroll 2
    for (int pass = 0; pass < 32; pass++) {
      int o = w * 32 + pass;
      const float4* wr = (const float4*)(fc1_w + (size_t)o * 1024);
      float sa = 0, sb = 0, sc = 0, sd = 0;
#pragma unroll
      for (int r = 0; r < 4; r++) {
        float4 wv = wr[r * 64 + lane];
        sa = fmaf(wv.x, u[r].x, sa); sb = fmaf(wv.y, u[r].y, sb);
        sc = fmaf(wv.z, u[r].z, sc); sd = fmaf(wv.w, u[r].w, sd);
      }
      float s = (sa + sb) + (sc + sd);
#pragma unroll
      for (int d = 1; d < 64; d <<= 1) s += __shfl_xor(s, d);
      if (lane == 0) {
        float t = s + fc1_b[o];
        h1[o] = LEAKY(t);
      }
    }
  }
  __syncthreads();
  {  // fc2: 16 waves x 16 outputs
    const float4* h1v = (const float4*)h1;
    float4 u0 = h1v[lane], u1 = h1v[64 + lane];
#pragma unroll 2
    for (int pass = 0; pass < 16; pass++) {
      int o = w * 16 + pass;
      const float4* wr = (const float4*)(fc2_w + (size_t)o * 512);
      float4 w0 = wr[lane], w1 = wr[64 + lane];
      float sa = fmaf(w0.x, u0.x, 0.f), sb = fmaf(w0.y, u0.y, 0.f);
      float sc = fmaf(w0.z, u0.z, 0.f), sd = fmaf(w0.w, u0.w, 0.f);
      sa = fmaf(w1.x, u1.x, sa); sb = fmaf(w1.y, u1.y, sb);
      sc = fmaf(w1.z, u1.z, sc); sd = fmaf(w1.w, u1.w, sd);
      float s = (sa + sb) + (sc + sd);
#pragma unroll
      for (int d = 1; d < 64; d <<= 1) s += __shfl_xor(s, d);
      if (lane == 0) {
        float t = s + fc2_b[o];
        h2[o] = LEAKY(t);
      }
    }
  }
  __syncthreads();
  if (w < 7) {  // heads: wave-per-output
    bool isrot = w < 4;
    int o = isrot ? w : w - 4;
    const float4* wr = (const float4*)((isrot ? fcr_w : fct_w) + (size_t)o * 256);
    const float4* uv = (const float4*)h2;
    float4 wv = wr[lane];
    float4 u = uv[lane];
    float s = fmaf(wv.x, u.x, fmaf(wv.y, u.y, fmaf(wv.z, u.z, wv.w * u.w)));
#pragma unroll
    for (int d = 1; d < 64; d <<= 1) s += __shfl_xor(s, d);
    if (lane == 0) {
      float t = s + (isrot ? fcr_b[o] : fct_b[o]);
      out[isrot ? (b * 4 + o) : (128 + b * 3 + o)] = t;
    }
  }
}

extern "C" void kernel_launch(void* const* d_in, const int* in_sizes, int n_in,
                              void* d_out, int out_size, void* d_ws, size_t ws_size,
                              hipStream_t stream) {
  const float* coor    = (const float*)d_in[0];
  const float* region  = (const float*)d_in[1];
  const float* extents = (const float*)d_in[2];
  const float* w1 = (const float*)d_in[3];  const float* b1 = (const float*)d_in[4];
  const float* w2 = (const float*)d_in[5];  const float* b2 = (const float*)d_in[6];
  const float* w3 = (const float*)d_in[7];  const float* b3 = (const float*)d_in[8];
  const float* w_sp = (const float*)d_in[9];  const float* b_sp = (const float*)d_in[10];
  const float* fc1_w = (const float*)d_in[11]; const float* fc1_b = (const float*)d_in[12];
  const float* fc2_w = (const float*)d_in[13]; const float* fc2_b = (const float*)d_in[14];
  const float* fcr_w = (const float*)d_in[15]; const float* fcr_b = (const float*)d_in[16];
  const float* fct_w = (const float*)d_in[17]; const float* fct_b = (const float*)d_in[18];

  char* ws = (char*)d_ws;
  unsigned* pool = (unsigned*)(ws + OFF_POOL);
  unsigned short* wsp = (unsigned short*)(ws + OFF_WSP);
  float* y32  = (float*)(ws + OFF_Y32);
  float* out  = (float*)d_out;

  kW<<<dim3(128), 256, 0, stream>>>(w2, w3, wsp, pool);
  kA<<<dim3(NTILES, NBATCH), 512, 0, stream>>>(coor, region, extents,
                                               w1, b1, b2, b3, wsp, pool);
  kC<<<dim3(32, 8), 256, 0, stream>>>(pool, w_sp, y32);
  kE<<<dim3(NBATCH), 1024, 0, stream>>>(y32, b_sp, fc1_w, fc1_b, fc2_w, fc2_b,
                                        fcr_w, fcr_b, fct_w, fct_b, out);
}

// Round 12
// 121.319 us; speedup vs baseline: 1.7368x; 1.0745x over previous
//
#include <hip/hip_runtime.h>
#include <cstddef>
#include <cstdint>

#define LEAKY(s) ((s) >= 0.f ? (s) : 0.1f * (s))

constexpr int PTS    = 4096;   // H*W
constexpr int NBATCH = 32;
constexpr int NM     = 8;      // regions
constexpr int TILE   = 128;    // points per block in kA
constexpr int NTILES = PTS / TILE;  // 32

// ---------------- workspace layout (bytes) ----------------
constexpr size_t OFF_POOL = 0;        // pool (B,1024) u32 (enc f32) 128KB
constexpr size_t OFF_WSP  = 131072;   // bf16 weights w2/w3 (A-frag order) 64KB
constexpr size_t OFF_Y32  = 262144;   // y32 (B,32,1024) f32 4MB

using bf16x8 = __attribute__((ext_vector_type(8))) short;
using f32x4v = __attribute__((ext_vector_type(4))) float;
using u16x4  = __attribute__((ext_vector_type(4))) unsigned short;
using u16x8  = __attribute__((ext_vector_type(8))) unsigned short;

// RNE round f32 -> bf16 (error ~2^-9 relative; numerically sufficient here:
// logits span only ~2e-3 so softmax/top-k sensitivity is ~1e-8 at outputs)
__device__ __forceinline__ unsigned short rbf(float x) {
  unsigned u = __float_as_uint(x);
  return (unsigned short)((u + 0x7FFFu + ((u >> 16) & 1u)) >> 16);
}

// monotone f32 <-> u32 encoding (order-preserving) for atomicMax pooling
__device__ __forceinline__ unsigned encf(float f) {
  unsigned u = __float_as_uint(f);
  return (u & 0x80000000u) ? ~u : (u | 0x80000000u);
}
__device__ __forceinline__ float decf(unsigned e) {
  unsigned u = (e & 0x80000000u) ? (e ^ 0x80000000u) : ~e;
  return __uint_as_float(u);
}

// swizzled byte offset into Xt[pt][k] bf16 array (row = 256B): XOR bits 4..6 by pt&7
__device__ __forceinline__ int swzb(int pt, int kByte) {
  return pt * 256 + (kByte ^ ((pt & 7) << 4));
}

// ============================================================
// Kernel W: round w2/w3 to bf16 in A-fragment order AND zero the pool.
// grid(128),256. elem = (((mt*4+kt)*4+l4)*16+l15)*8+e ; c=mt*16+l15, k=kt*32+l4*8+e
// ============================================================
__global__ __launch_bounds__(256) void kW(const float* __restrict__ w2,
                                          const float* __restrict__ w3,
                                          unsigned short* __restrict__ wsp,
                                          unsigned* __restrict__ pool) {
  int id = blockIdx.x * 256 + threadIdx.x;   // 0..32767
  pool[id] = 0u;                             // enc(x) > 0 for all finite x
  int layer = id >> 14, e16 = id & 16383;
  int e = e16 & 7, l15 = (e16 >> 3) & 15, l4 = (e16 >> 7) & 3,
      kt = (e16 >> 9) & 3, mt = e16 >> 11;
  int c = mt * 16 + l15, k = kt * 32 + l4 * 8 + e;
  float v = (layer ? w3 : w2)[c * 128 + k];
  wsp[layer * 16384 + e16] = rbf(v);
}

// ============================================================
// Kernel A: conv1 -> conv2 -> conv3 (single-bf16 MFMA) -> masked-max ->
// atomicMax pool. grid (NTILES=32, B), 512 thr / 8 waves, 36.6KB LDS
// -> 4 blocks/CU = 8 waves/SIMD. Wave mt owns 16 out-channels x 128 pts.
// ============================================================
__device__ __forceinline__ void mfmaLayer8s(const unsigned short* __restrict__ W,
                                            const float* __restrict__ bias,
                                            const char* Xc,
                                            int lane, int mt, f32x4v acc[8]) {
  const int l15 = lane & 15, l4 = lane >> 4;
  {
    float4 bv = *(const float4*)(bias + mt * 16 + l4 * 4);
    f32x4v b4; b4[0] = bv.x; b4[1] = bv.y; b4[2] = bv.z; b4[3] = bv.w;
#pragma unroll
    for (int nt = 0; nt < 8; nt++) acc[nt] = b4;
  }
#pragma unroll
  for (int kt = 0; kt < 4; kt++) {
    int woff = (((mt * 4 + kt) * 4 + l4) * 16 + l15) * 8;
    bf16x8 ah = *(const bf16x8*)(W + woff);
    const int kb = (kt * 32 + l4 * 8) * 2;
#pragma unroll
    for (int nt = 0; nt < 8; nt++) {
      bf16x8 bh = *(const bf16x8*)(Xc + swzb(nt * 16 + l15, kb));
      acc[nt] = __builtin_amdgcn_mfma_f32_16x16x32_bf16(ah, bh, acc[nt], 0, 0, 0);
    }
  }
}

__global__ __launch_bounds__(512, 8) void kA(
    const float* __restrict__ coor, const float* __restrict__ region,
    const float* __restrict__ extents,
    const float* __restrict__ w1, const float* __restrict__ b1,
    const float* __restrict__ b2, const float* __restrict__ b3,
    const unsigned short* __restrict__ wsp,
    unsigned* __restrict__ pool) {
  __shared__ unsigned short X[128 * 128];   // 32KB bf16 acts (f32 funnel aliases)
  __shared__ float reg_s[NM * TILE];        // 4KB
  const int tid = threadIdx.x;
  const int b = blockIdx.y;
  const int t0 = blockIdx.x * TILE;
  const int lane = tid & 63;
  const int wv = tid >> 6;                  // 0..7
  char* Xc = (char*)X;

  {  // stage region tile: 8 rows x 128 (float2/thread)
    int m = tid >> 6, j = tid & 63;
    float2 v = *(const float2*)(region + ((size_t)b * NM + m) * PTS + t0 + j * 2);
    *(float2*)(reg_s + m * TILE + j * 2) = v;
  }
  {  // layer 1 (K=5): thread = (pt, ch-quarter); writes X bf16
    const int pt = tid & 127;
    const int chq = (tid >> 7) * 32;
    float e0 = extents[b * 3], e1 = extents[b * 3 + 1], e2 = extents[b * 3 + 2];
    float in5[5];
#pragma unroll
    for (int i = 0; i < 5; i++) in5[i] = coor[((size_t)b * 5 + i) * PTS + t0 + pt];
    in5[0] = (in5[0] - 0.5f) * e0;
    in5[1] = (in5[1] - 0.5f) * e1;
    in5[2] = (in5[2] - 0.5f) * e2;
#pragma unroll
    for (int c8 = 0; c8 < 32; c8 += 8) {
      u16x8 hh;
#pragma unroll
      for (int q = 0; q < 8; q++) {
        int c = chq + c8 + q;
        float s = b1[c];
#pragma unroll
        for (int i = 0; i < 5; i++) s = fmaf(w1[c * 5 + i], in5[i], s);
        s = LEAKY(s);
        hh[q] = rbf(s);
      }
      int off = swzb(pt, (chq + c8) * 2);
      *(u16x8*)(Xc + off) = hh;
    }
  }
  __syncthreads();

  f32x4v acc[8];
  const int mt = wv;
  const int l15 = lane & 15, l4 = lane >> 4;

  // layer 2
  mfmaLayer8s(wsp, b2, Xc, lane, mt, acc);
  __syncthreads();
  {  // leaky + round + write act2 back to X (ch0 = mt*16 + l4*4, pts nt*16+l15)
    const int ch0 = mt * 16 + l4 * 4;
#pragma unroll
    for (int nt = 0; nt < 8; nt++) {
      u16x4 h4;
#pragma unroll
      for (int r = 0; r < 4; r++) {
        float s = acc[nt][r];
        s = LEAKY(s);
        h4[r] = rbf(s);
      }
      int off = swzb(nt * 16 + l15, ch0 * 2);
      *(u16x4*)(Xc + off) = h4;
    }
  }
  __syncthreads();
  // layer 3 (bias, no activation)
  mfmaLayer8s(wsp + 16384, b3, Xc, lane, mt, acc);
  __syncthreads();  // all X reads done; reuse X as f32 funnel

  {  // region-masked max -> funnel[c*8+m]
    float* funnel = (float*)X;
#pragma unroll
    for (int m = 0; m < NM; m++) {
      float rv[8];
#pragma unroll
      for (int nt = 0; nt < 8; nt++) rv[nt] = reg_s[m * TILE + nt * 16 + l15];
#pragma unroll
      for (int r = 0; r < 4; r++) {
        float mx = acc[0][r] * rv[0];
#pragma unroll
        for (int nt = 1; nt < 8; nt++) mx = fmaxf(mx, acc[nt][r] * rv[nt]);
        mx = fmaxf(mx, __shfl_xor(mx, 1));
        mx = fmaxf(mx, __shfl_xor(mx, 2));
        mx = fmaxf(mx, __shfl_xor(mx, 4));
        mx = fmaxf(mx, __shfl_xor(mx, 8));
        if (l15 == 0) funnel[(mt * 16 + l4 * 4 + r) * 8 + m] = mx;
      }
    }
  }
  __syncthreads();
  {  // order-independent pool: atomicMax of monotone-encoded f32 (2/thread)
    const float* fun = (const float*)X;
    unsigned* pl = pool + (size_t)b * 1024;
    atomicMax(pl + tid, encf(fun[tid]));
    atomicMax(pl + tid + 512, encf(fun[tid + 512]));
  }
}

// ============================================================
// Kernel C (R8 best): decode pool -> softmax -> per-k sort ->
// GEMM D[b,k,m,o] = sum_c xs[c,m]*w_sp[o,c,k] -> fused gather-sum -> y32.
// grid (32 ktiles of 4, 8 bgroups of 4), 256 thr. As stride 516.
// T14 prefetch: next c0 chunk's global loads issued before compute.
// ============================================================
__global__ __launch_bounds__(256) void kC(const unsigned* __restrict__ pool,
                                          const float* __restrict__ w_sp,
                                          float* __restrict__ y32) {
  __shared__ float As[16 * 516];     // 33KB
  __shared__ float xsl[4 * 128 * 8]; // 16KB  [bl][c][m]
  __shared__ int idxL[4][4][8];      // [bl][kk][r]
  const int tid = threadIdx.x;
  const int k0 = blockIdx.x * 4;
  const int bbase = blockIdx.y * 4;
  const int rg = tid & 63, cgq = tid >> 6;

  // decode pool (4 b x 1024) -> xsl
#pragma unroll
  for (int it = 0; it < 4; it++) {
    uint4 v = *(const uint4*)(pool + (size_t)(bbase + it) * 1024 + tid * 4);
    float4 f = {decf(v.x), decf(v.y), decf(v.z), decf(v.w)};
    *(float4*)(xsl + it * 1024 + tid * 4) = f;
  }
  // prologue: issue c0=0 staging loads
  float4 wreg[8];
#pragma unroll
  for (int it = 0; it < 8; it++) {
    int q = tid + it * 256, o = q >> 4, cc = q & 15;
    wreg[it] = *(const float4*)(w_sp + (size_t)o * 16384 + (size_t)cc * 128 + k0);
  }
  __syncthreads();
  {  // softmax over c per (bl, m): 32 pairs x 8 threads
    int pair = tid >> 3, sub = tid & 7;
    int bl = pair >> 3, m = pair & 7;
    float* base = xsl + bl * 1024 + m;
    float v[16];
#pragma unroll
    for (int j = 0; j < 16; j++) v[j] = base[(sub + 8 * j) * 8];
    float mx = v[0];
#pragma unroll
    for (int j = 1; j < 16; j++) mx = fmaxf(mx, v[j]);
    mx = fmaxf(mx, __shfl_xor(mx, 1));
    mx = fmaxf(mx, __shfl_xor(mx, 2));
    mx = fmaxf(mx, __shfl_xor(mx, 4));
    float s = 0.f;
#pragma unroll
    for (int j = 0; j < 16; j++) { v[j] = expf(v[j] - mx); s += v[j]; }
    s += __shfl_xor(s, 1);
    s += __shfl_xor(s, 2);
    s += __shfl_xor(s, 4);
    float inv = 1.f / s;
#pragma unroll
    for (int j = 0; j < 16; j++) base[(sub + 8 * j) * 8] = v[j] * inv;
  }
  __syncthreads();
  if (tid < 16) {  // sort this block's 4 k-channels per batch
    int bl = tid >> 2, kk = tid & 3;
    float vv[8];
#pragma unroll
    for (int n = 0; n < 8; n++) vv[n] = xsl[bl * 1024 + (k0 + kk) * 8 + n];
    int used = 0;
#pragma unroll
    for (int n = 0; n < 8; n++) {
      int best = 0; float bv = -1.f;
#pragma unroll
      for (int q = 0; q < 8; q++) {
        bool ok = ((used >> q) & 1) == 0;
        if (ok && vv[q] > bv) { bv = vv[q]; best = q; }  // strict > == lowest-index tie-break
      }
      used |= 1 << best;
      idxL[bl][kk][n] = best;
    }
  }

  float acc[8][8];
#pragma unroll
  for (int i = 0; i < 8; i++)
#pragma unroll
    for (int j = 0; j < 8; j++) acc[i][j] = 0.f;

  for (int c0 = 0; c0 < 128; c0 += 16) {
    __syncthreads();  // As free (consumed by previous compute)
#pragma unroll
    for (int it = 0; it < 8; it++) {
      int q = tid + it * 256, o = q >> 4, cc = q & 15;
      As[cc * 516 + o]       = wreg[it].x;
      As[cc * 516 + 128 + o] = wreg[it].y;
      As[cc * 516 + 256 + o] = wreg[it].z;
      As[cc * 516 + 384 + o] = wreg[it].w;
    }
    __syncthreads();
    if (c0 + 16 < 128) {  // issue next chunk early (hidden under compute)
#pragma unroll
      for (int it = 0; it < 8; it++) {
        int q = tid + it * 256, o = q >> 4, cc = q & 15;
        wreg[it] = *(const float4*)(w_sp + (size_t)o * 16384 + (size_t)(c0 + 16 + cc) * 128 + k0);
      }
    }
#pragma unroll
    for (int cc = 0; cc < 16; cc++) {
      float4 a0 = *(const float4*)(As + cc * 516 + rg * 4);
      float4 a1 = *(const float4*)(As + cc * 516 + 256 + rg * 4);
      float4 p0 = *(const float4*)(xsl + cgq * 1024 + (c0 + cc) * 8);      // broadcast
      float4 p1 = *(const float4*)(xsl + cgq * 1024 + (c0 + cc) * 8 + 4);  // broadcast
      float av[8] = {a0.x, a0.y, a0.z, a0.w, a1.x, a1.y, a1.z, a1.w};
      float bv[8] = {p0.x, p0.y, p0.z, p0.w, p1.x, p1.y, p1.z, p1.w};
#pragma unroll
      for (int i = 0; i < 8; i++)
#pragma unroll
        for (int j = 0; j < 8; j++) acc[i][j] = fmaf(av[i], bv[j], acc[i][j]);
    }
  }
  // gather-sum epilogue. acc rows: i<4 -> row rg*4+i (kk=rg>>5, o=row&127);
  // i>=4 -> row 256+rg*4+(i-4) (kk=2+(rg>>5)). wave cgq owns batch bbase+cgq.
  const int rgl = rg & 31;
  const int kkA = rg >> 5;
  int msA[8], msB[8];
#pragma unroll
  for (int r = 0; r < 8; r++) {
    msA[r] = idxL[cgq][kkA][r];
    msB[r] = idxL[cgq][2 + kkA][r];
  }
  float yp[4][8];
#pragma unroll
  for (int i4 = 0; i4 < 4; i4++) {
#pragma unroll
    for (int r = 0; r < 8; r++) {
      float v = 0.f;
#pragma unroll
      for (int j = 0; j < 8; j++) {
        v += (j == msA[r]) ? acc[i4][j] : 0.f;
        v += (j == msB[r]) ? acc[i4 + 4][j] : 0.f;
      }
      yp[i4][r] = v;
    }
  }
#pragma unroll
  for (int i4 = 0; i4 < 4; i4++)
#pragma unroll
    for (int r = 0; r < 8; r++) yp[i4][r] += __shfl_xor(yp[i4][r], 32);
  if (rg < 32) {  // lane rg holds o = rg*4+i4, summed over 4 kk
    float* dst = y32 + ((size_t)(bbase + cgq) * 32 + blockIdx.x) * 1024 + rgl * 32;
#pragma unroll
    for (int i4 = 0; i4 < 4; i4++) {
      float4 v0 = {yp[i4][0], yp[i4][1], yp[i4][2], yp[i4][3]};
      float4 v1 = {yp[i4][4], yp[i4][5], yp[i4][6], yp[i4][7]};
      *(float4*)(dst + i4 * 8) = v0;
      *(float4*)(dst + i4 * 8 + 4) = v1;
    }
  }
}

// ============================================================
// Kernel E: assemble y (sum 32 tiles + b_sp + leaky) -> fc1 -> fc2 -> heads.
// grid (B), 1024 thr (16 waves).
// ============================================================
__global__ __launch_bounds__(1024) void kE(
    const float* __restrict__ y32, const float* __restrict__ b_sp,
    const float* __restrict__ fc1_w, const float* __restrict__ fc1_b,
    const float* __restrict__ fc2_w, const float* __restrict__ fc2_b,
    const float* __restrict__ fcr_w, const float* __restrict__ fcr_b,
    const float* __restrict__ fct_w, const float* __restrict__ fct_b,
    float* __restrict__ out) {
  __shared__ float yl[1024];
  __shared__ float h1[512];
  __shared__ float h2[256];
  int b = blockIdx.x, tid = threadIdx.x;
  int w = tid >> 6, lane = tid & 63;
  {  // assemble y: thread per feature
    const float* base = y32 + (size_t)b * 32768 + tid;
    float s = 0.f;
#pragma unroll 8
    for (int t = 0; t < 32; t++) s += base[t * 1024];
    s += b_sp[tid >> 3];
    yl[tid] = LEAKY(s);
  }
  __syncthreads();
  {  // fc1: 16 waves x 32 outputs
    const float4* ylv = (const float4*)yl;
    float4 u[4];
#pragma unroll
    for (int r = 0; r < 4; r++) u[r] = ylv[r * 64 + lane];
#pragma unroll 2
    for (int pass = 0; pass < 32; pass++) {
      int o = w * 32 + pass;
      const float4* wr = (const float4*)(fc1_w + (size_t)o * 1024);
      float sa = 0, sb = 0, sc = 0, sd = 0;
#pragma unroll
      for (int r = 0; r < 4; r++) {
        float4 wv = wr[r * 64 + lane];
        sa = fmaf(wv.x, u[r].x, sa); sb = fmaf(wv.y, u[r].y, sb);
        sc = fmaf(wv.z, u[r].z, sc); sd = fmaf(wv.w, u[r].w, sd);
      }
      float s = (sa + sb) + (sc + sd);
#pragma unroll
      for (int d = 1; d < 64; d <<= 1) s += __shfl_xor(s, d);
      if (lane == 0) {
        float t = s + fc1_b[o];
        h1[o] = LEAKY(t);
      }
    }
  }
  __syncthreads();
  {  // fc2: 16 waves x 16 outputs
    const float4* h1v = (const float4*)h1;
    float4 u0 = h1v[lane], u1 = h1v[64 + lane];
#pragma unroll 2
    for (int pass = 0; pass < 16; pass++) {
      int o = w * 16 + pass;
      const float4* wr = (const float4*)(fc2_w + (size_t)o * 512);
      float4 w0 = wr[lane], w1 = wr[64 + lane];
      float sa = fmaf(w0.x, u0.x, 0.f), sb = fmaf(w0.y, u0.y, 0.f);
      float sc = fmaf(w0.z, u0.z, 0.f), sd = fmaf(w0.w, u0.w, 0.f);
      sa = fmaf(w1.x, u1.x, sa); sb = fmaf(w1.y, u1.y, sb);
      sc = fmaf(w1.z, u1.z, sc); sd = fmaf(w1.w, u1.w, sd);
      float s = (sa + sb) + (sc + sd);
#pragma unroll
      for (int d = 1; d < 64; d <<= 1) s += __shfl_xor(s, d);
      if (lane == 0) {
        float t = s + fc2_b[o];
        h2[o] = LEAKY(t);
      }
    }
  }
  __syncthreads();
  if (w < 7) {  // heads: wave-per-output
    bool isrot = w < 4;
    int o = isrot ? w : w - 4;
    const float4* wr = (const float4*)((isrot ? fcr_w : fct_w) + (size_t)o * 256);
    const float4* uv = (const float4*)h2;
    float4 wv = wr[lane];
    float4 u = uv[lane];
    float s = fmaf(wv.x, u.x, fmaf(wv.y, u.y, fmaf(wv.z, u.z, wv.w * u.w)));
#pragma unroll
    for (int d = 1; d < 64; d <<= 1) s += __shfl_xor(s, d);
    if (lane == 0) {
      float t = s + (isrot ? fcr_b[o] : fct_b[o]);
      out[isrot ? (b * 4 + o) : (128 + b * 3 + o)] = t;
    }
  }
}

extern "C" void kernel_launch(void* const* d_in, const int* in_sizes, int n_in,
                              void* d_out, int out_size, void* d_ws, size_t ws_size,
                              hipStream_t stream) {
  const float* coor    = (const float*)d_in[0];
  const float* region  = (const float*)d_in[1];
  const float* extents = (const float*)d_in[2];
  const float* w1 = (const float*)d_in[3];  const float* b1 = (const float*)d_in[4];
  const float* w2 = (const float*)d_in[5];  const float* b2 = (const float*)d_in[6];
  const float* w3 = (const float*)d_in[7];  const float* b3 = (const float*)d_in[8];
  const float* w_sp = (const float*)d_in[9];  const float* b_sp = (const float*)d_in[10];
  const float* fc1_w = (const float*)d_in[11]; const float* fc1_b = (const float*)d_in[12];
  const float* fc2_w = (const float*)d_in[13]; const float* fc2_b = (const float*)d_in[14];
  const float* fcr_w = (const float*)d_in[15]; const float* fcr_b = (const float*)d_in[16];
  const float* fct_w = (const float*)d_in[17]; const float* fct_b = (const float*)d_in[18];

  char* ws = (char*)d_ws;
  unsigned* pool = (unsigned*)(ws + OFF_POOL);
  unsigned short* wsp = (unsigned short*)(ws + OFF_WSP);
  float* y32  = (float*)(ws + OFF_Y32);
  float* out  = (float*)d_out;

  kW<<<dim3(128), 256, 0, stream>>>(w2, w3, wsp, pool);
  kA<<<dim3(NTILES, NBATCH), 512, 0, stream>>>(coor, region, extents,
                                               w1, b1, b2, b3, wsp, pool);
  kC<<<dim3(32, 8), 256, 0, stream>>>(pool, w_sp, y32);
  kE<<<dim3(NBATCH), 1024, 0, stream>>>(y32, b_sp, fc1_w, fc1_b, fc2_w, fc2_b,
                                        fcr_w, fcr_b, fct_w, fct_b, out);
}

// Round 13
// 108.390 us; speedup vs baseline: 1.9439x; 1.1193x over previous
//
#include <hip/hip_runtime.h>
#include <cstddef>
#include <cstdint>

#define LEAKY(s) ((s) >= 0.f ? (s) : 0.1f * (s))

constexpr int PTS    = 4096;   // H*W
constexpr int NBATCH = 32;
constexpr int NM     = 8;      // regions
constexpr int TILE   = 128;    // points per block in kA
constexpr int NTILES = PTS / TILE;  // 32

// ---------------- workspace layout (bytes) ----------------
constexpr size_t OFF_POOL = 0;        // pool (B,1024) u32 (enc f32) 128KB
constexpr size_t OFF_WSP  = 131072;   // bf16 weights w2/w3 (A-frag order) 64KB
constexpr size_t OFF_Y32  = 262144;   // y32 (B,32,1024) f32 4MB
constexpr size_t OFF_Y    = 4456448;  // y (B,1024) f32 128KB
constexpr size_t OFF_H1   = 4587520;  // h1 (B,512) f32 64KB

using bf16x8 = __attribute__((ext_vector_type(8))) short;
using f32x4v = __attribute__((ext_vector_type(4))) float;
using u16x4  = __attribute__((ext_vector_type(4))) unsigned short;
using u16x8  = __attribute__((ext_vector_type(8))) unsigned short;

// RNE round f32 -> bf16 (sufficient: logits span ~2e-3; sensitivity ~1e-8 at out)
__device__ __forceinline__ unsigned short rbf(float x) {
  unsigned u = __float_as_uint(x);
  return (unsigned short)((u + 0x7FFFu + ((u >> 16) & 1u)) >> 16);
}

// monotone f32 <-> u32 encoding (order-preserving) for atomicMax pooling
__device__ __forceinline__ unsigned encf(float f) {
  unsigned u = __float_as_uint(f);
  return (u & 0x80000000u) ? ~u : (u | 0x80000000u);
}
__device__ __forceinline__ float decf(unsigned e) {
  unsigned u = (e & 0x80000000u) ? (e ^ 0x80000000u) : ~e;
  return __uint_as_float(u);
}

// swizzled byte offset into Xt[pt][k] bf16 array (row = 256B): XOR bits 4..6 by pt&7
__device__ __forceinline__ int swzb(int pt, int kByte) {
  return pt * 256 + (kByte ^ ((pt & 7) << 4));
}

// ============================================================
// Kernel W: round w2/w3 to bf16 in A-fragment order AND zero the pool.
// ============================================================
__global__ __launch_bounds__(256) void kW(const float* __restrict__ w2,
                                          const float* __restrict__ w3,
                                          unsigned short* __restrict__ wsp,
                                          unsigned* __restrict__ pool) {
  int id = blockIdx.x * 256 + threadIdx.x;   // 0..32767
  pool[id] = 0u;                             // enc(x) > 0 for all finite x
  int layer = id >> 14, e16 = id & 16383;
  int e = e16 & 7, l15 = (e16 >> 3) & 15, l4 = (e16 >> 7) & 3,
      kt = (e16 >> 9) & 3, mt = e16 >> 11;
  int c = mt * 16 + l15, k = kt * 32 + l4 * 8 + e;
  float v = (layer ? w3 : w2)[c * 128 + k];
  wsp[layer * 16384 + e16] = rbf(v);
}

// ============================================================
// Kernel A (R12): conv1 -> conv2 -> conv3 (single-bf16 MFMA) -> masked-max
// -> atomicMax pool. grid (NTILES=32, B), 512 thr / 8 waves, 4 blocks/CU.
// ============================================================
__device__ __forceinline__ void mfmaLayer8s(const unsigned short* __restrict__ W,
                                            const float* __restrict__ bias,
                                            const char* Xc,
                                            int lane, int mt, f32x4v acc[8]) {
  const int l15 = lane & 15, l4 = lane >> 4;
  {
    float4 bv = *(const float4*)(bias + mt * 16 + l4 * 4);
    f32x4v b4; b4[0] = bv.x; b4[1] = bv.y; b4[2] = bv.z; b4[3] = bv.w;
#pragma unroll
    for (int nt = 0; nt < 8; nt++) acc[nt] = b4;
  }
#pragma unroll
  for (int kt = 0; kt < 4; kt++) {
    int woff = (((mt * 4 + kt) * 4 + l4) * 16 + l15) * 8;
    bf16x8 ah = *(const bf16x8*)(W + woff);
    const int kb = (kt * 32 + l4 * 8) * 2;
#pragma unroll
    for (int nt = 0; nt < 8; nt++) {
      bf16x8 bh = *(const bf16x8*)(Xc + swzb(nt * 16 + l15, kb));
      acc[nt] = __builtin_amdgcn_mfma_f32_16x16x32_bf16(ah, bh, acc[nt], 0, 0, 0);
    }
  }
}

__global__ __launch_bounds__(512, 8) void kA(
    const float* __restrict__ coor, const float* __restrict__ region,
    const float* __restrict__ extents,
    const float* __restrict__ w1, const float* __restrict__ b1,
    const float* __restrict__ b2, const float* __restrict__ b3,
    const unsigned short* __restrict__ wsp,
    unsigned* __restrict__ pool) {
  __shared__ unsigned short X[128 * 128];   // 32KB bf16 acts (f32 funnel aliases)
  __shared__ float reg_s[NM * TILE];        // 4KB
  const int tid = threadIdx.x;
  const int b = blockIdx.y;
  const int t0 = blockIdx.x * TILE;
  const int lane = tid & 63;
  const int wv = tid >> 6;                  // 0..7
  char* Xc = (char*)X;

  {  // stage region tile: 8 rows x 128 (float2/thread)
    int m = tid >> 6, j = tid & 63;
    float2 v = *(const float2*)(region + ((size_t)b * NM + m) * PTS + t0 + j * 2);
    *(float2*)(reg_s + m * TILE + j * 2) = v;
  }
  {  // layer 1 (K=5): thread = (pt, ch-quarter); writes X bf16
    const int pt = tid & 127;
    const int chq = (tid >> 7) * 32;
    float e0 = extents[b * 3], e1 = extents[b * 3 + 1], e2 = extents[b * 3 + 2];
    float in5[5];
#pragma unroll
    for (int i = 0; i < 5; i++) in5[i] = coor[((size_t)b * 5 + i) * PTS + t0 + pt];
    in5[0] = (in5[0] - 0.5f) * e0;
    in5[1] = (in5[1] - 0.5f) * e1;
    in5[2] = (in5[2] - 0.5f) * e2;
#pragma unroll
    for (int c8 = 0; c8 < 32; c8 += 8) {
      u16x8 hh;
#pragma unroll
      for (int q = 0; q < 8; q++) {
        int c = chq + c8 + q;
        float s = b1[c];
#pragma unroll
        for (int i = 0; i < 5; i++) s = fmaf(w1[c * 5 + i], in5[i], s);
        s = LEAKY(s);
        hh[q] = rbf(s);
      }
      int off = swzb(pt, (chq + c8) * 2);
      *(u16x8*)(Xc + off) = hh;
    }
  }
  __syncthreads();

  f32x4v acc[8];
  const int mt = wv;
  const int l15 = lane & 15, l4 = lane >> 4;

  // layer 2
  mfmaLayer8s(wsp, b2, Xc, lane, mt, acc);
  __syncthreads();
  {  // leaky + round + write act2 back to X
    const int ch0 = mt * 16 + l4 * 4;
#pragma unroll
    for (int nt = 0; nt < 8; nt++) {
      u16x4 h4;
#pragma unroll
      for (int r = 0; r < 4; r++) {
        float s = acc[nt][r];
        s = LEAKY(s);
        h4[r] = rbf(s);
      }
      int off = swzb(nt * 16 + l15, ch0 * 2);
      *(u16x4*)(Xc + off) = h4;
    }
  }
  __syncthreads();
  // layer 3 (bias, no activation)
  mfmaLayer8s(wsp + 16384, b3, Xc, lane, mt, acc);
  __syncthreads();  // all X reads done; reuse X as f32 funnel

  {  // region-masked max -> funnel[c*8+m]
    float* funnel = (float*)X;
#pragma unroll
    for (int m = 0; m < NM; m++) {
      float rv[8];
#pragma unroll
      for (int nt = 0; nt < 8; nt++) rv[nt] = reg_s[m * TILE + nt * 16 + l15];
#pragma unroll
      for (int r = 0; r < 4; r++) {
        float mx = acc[0][r] * rv[0];
#pragma unroll
        for (int nt = 1; nt < 8; nt++) mx = fmaxf(mx, acc[nt][r] * rv[nt]);
        mx = fmaxf(mx, __shfl_xor(mx, 1));
        mx = fmaxf(mx, __shfl_xor(mx, 2));
        mx = fmaxf(mx, __shfl_xor(mx, 4));
        mx = fmaxf(mx, __shfl_xor(mx, 8));
        if (l15 == 0) funnel[(mt * 16 + l4 * 4 + r) * 8 + m] = mx;
      }
    }
  }
  __syncthreads();
  {  // order-independent pool: atomicMax of monotone-encoded f32 (2/thread)
    const float* fun = (const float*)X;
    unsigned* pl = pool + (size_t)b * 1024;
    atomicMax(pl + tid, encf(fun[tid]));
    atomicMax(pl + tid + 512, encf(fun[tid + 512]));
  }
}

// ============================================================
// Kernel C (R12): decode pool -> softmax -> per-k sort ->
// GEMM + fused gather-sum -> y32. grid (32,8), 256 thr. As stride 516.
// ============================================================
__global__ __launch_bounds__(256) void kC(const unsigned* __restrict__ pool,
                                          const float* __restrict__ w_sp,
                                          float* __restrict__ y32) {
  __shared__ float As[16 * 516];     // 33KB
  __shared__ float xsl[4 * 128 * 8]; // 16KB  [bl][c][m]
  __shared__ int idxL[4][4][8];      // [bl][kk][r]
  const int tid = threadIdx.x;
  const int k0 = blockIdx.x * 4;
  const int bbase = blockIdx.y * 4;
  const int rg = tid & 63, cgq = tid >> 6;

#pragma unroll
  for (int it = 0; it < 4; it++) {
    uint4 v = *(const uint4*)(pool + (size_t)(bbase + it) * 1024 + tid * 4);
    float4 f = {decf(v.x), decf(v.y), decf(v.z), decf(v.w)};
    *(float4*)(xsl + it * 1024 + tid * 4) = f;
  }
  float4 wreg[8];
#pragma unroll
  for (int it = 0; it < 8; it++) {
    int q = tid + it * 256, o = q >> 4, cc = q & 15;
    wreg[it] = *(const float4*)(w_sp + (size_t)o * 16384 + (size_t)cc * 128 + k0);
  }
  __syncthreads();
  {  // softmax over c per (bl, m): 32 pairs x 8 threads
    int pair = tid >> 3, sub = tid & 7;
    int bl = pair >> 3, m = pair & 7;
    float* base = xsl + bl * 1024 + m;
    float v[16];
#pragma unroll
    for (int j = 0; j < 16; j++) v[j] = base[(sub + 8 * j) * 8];
    float mx = v[0];
#pragma unroll
    for (int j = 1; j < 16; j++) mx = fmaxf(mx, v[j]);
    mx = fmaxf(mx, __shfl_xor(mx, 1));
    mx = fmaxf(mx, __shfl_xor(mx, 2));
    mx = fmaxf(mx, __shfl_xor(mx, 4));
    float s = 0.f;
#pragma unroll
    for (int j = 0; j < 16; j++) { v[j] = expf(v[j] - mx); s += v[j]; }
    s += __shfl_xor(s, 1);
    s += __shfl_xor(s, 2);
    s += __shfl_xor(s, 4);
    float inv = 1.f / s;
#pragma unroll
    for (int j = 0; j < 16; j++) base[(sub + 8 * j) * 8] = v[j] * inv;
  }
  __syncthreads();
  if (tid < 16) {  // sort this block's 4 k-channels per batch
    int bl = tid >> 2, kk = tid & 3;
    float vv[8];
#pragma unroll
    for (int n = 0; n < 8; n++) vv[n] = xsl[bl * 1024 + (k0 + kk) * 8 + n];
    int used = 0;
#pragma unroll
    for (int n = 0; n < 8; n++) {
      int best = 0; float bv = -1.f;
#pragma unroll
      for (int q = 0; q < 8; q++) {
        bool ok = ((used >> q) & 1) == 0;
        if (ok && vv[q] > bv) { bv = vv[q]; best = q; }  // strict > == lowest-index tie-break
      }
      used |= 1 << best;
      idxL[bl][kk][n] = best;
    }
  }

  float acc[8][8];
#pragma unroll
  for (int i = 0; i < 8; i++)
#pragma unroll
    for (int j = 0; j < 8; j++) acc[i][j] = 0.f;

  for (int c0 = 0; c0 < 128; c0 += 16) {
    __syncthreads();
#pragma unroll
    for (int it = 0; it < 8; it++) {
      int q = tid + it * 256, o = q >> 4, cc = q & 15;
      As[cc * 516 + o]       = wreg[it].x;
      As[cc * 516 + 128 + o] = wreg[it].y;
      As[cc * 516 + 256 + o] = wreg[it].z;
      As[cc * 516 + 384 + o] = wreg[it].w;
    }
    __syncthreads();
    if (c0 + 16 < 128) {
#pragma unroll
      for (int it = 0; it < 8; it++) {
        int q = tid + it * 256, o = q >> 4, cc = q & 15;
        wreg[it] = *(const float4*)(w_sp + (size_t)o * 16384 + (size_t)(c0 + 16 + cc) * 128 + k0);
      }
    }
#pragma unroll
    for (int cc = 0; cc < 16; cc++) {
      float4 a0 = *(const float4*)(As + cc * 516 + rg * 4);
      float4 a1 = *(const float4*)(As + cc * 516 + 256 + rg * 4);
      float4 p0 = *(const float4*)(xsl + cgq * 1024 + (c0 + cc) * 8);      // broadcast
      float4 p1 = *(const float4*)(xsl + cgq * 1024 + (c0 + cc) * 8 + 4);  // broadcast
      float av[8] = {a0.x, a0.y, a0.z, a0.w, a1.x, a1.y, a1.z, a1.w};
      float bv[8] = {p0.x, p0.y, p0.z, p0.w, p1.x, p1.y, p1.z, p1.w};
#pragma unroll
      for (int i = 0; i < 8; i++)
#pragma unroll
        for (int j = 0; j < 8; j++) acc[i][j] = fmaf(av[i], bv[j], acc[i][j]);
    }
  }
  const int rgl = rg & 31;
  const int kkA = rg >> 5;
  int msA[8], msB[8];
#pragma unroll
  for (int r = 0; r < 8; r++) {
    msA[r] = idxL[cgq][kkA][r];
    msB[r] = idxL[cgq][2 + kkA][r];
  }
  float yp[4][8];
#pragma unroll
  for (int i4 = 0; i4 < 4; i4++) {
#pragma unroll
    for (int r = 0; r < 8; r++) {
      float v = 0.f;
#pragma unroll
      for (int j = 0; j < 8; j++) {
        v += (j == msA[r]) ? acc[i4][j] : 0.f;
        v += (j == msB[r]) ? acc[i4 + 4][j] : 0.f;
      }
      yp[i4][r] = v;
    }
  }
#pragma unroll
  for (int i4 = 0; i4 < 4; i4++)
#pragma unroll
    for (int r = 0; r < 8; r++) yp[i4][r] += __shfl_xor(yp[i4][r], 32);
  if (rg < 32) {
    float* dst = y32 + ((size_t)(bbase + cgq) * 32 + blockIdx.x) * 1024 + rgl * 32;
#pragma unroll
    for (int i4 = 0; i4 < 4; i4++) {
      float4 v0 = {yp[i4][0], yp[i4][1], yp[i4][2], yp[i4][3]};
      float4 v1 = {yp[i4][4], yp[i4][5], yp[i4][6], yp[i4][7]};
      *(float4*)(dst + i4 * 8) = v0;
      *(float4*)(dst + i4 * 8 + 4) = v1;
    }
  }
}

// ============================================================
// Kernel Y: y[b][f] = leaky(sum_t y32[b][t][f] + b_sp[f>>3]).
// grid (4 fgroups, B) = 128 blocks, 256 thr, thread-per-feature.
// ============================================================
__global__ __launch_bounds__(256) void kY(const float* __restrict__ y32,
                                          const float* __restrict__ b_sp,
                                          float* __restrict__ y) {
  int fg = blockIdx.x, b = blockIdx.y, tid = threadIdx.x;
  int f = fg * 256 + tid;
  const float* base = y32 + (size_t)b * 32768 + f;
  float s = 0.f;
#pragma unroll 8
  for (int t = 0; t < 32; t++) s += base[t * 1024];
  s += b_sp[f >> 3];
  y[(size_t)b * 1024 + f] = LEAKY(s);
}

// ============================================================
// Kernel E1: fc1 -> h1. grid (8 ogroups, B) = 256 blocks, 256 thr (4 waves);
// wave-per-output passes, coalesced 4KB weight rows; y[b] from global (L2-hot).
// ============================================================
__global__ __launch_bounds__(256) void kE1(
    const float* __restrict__ y, const float* __restrict__ fc1_w,
    const float* __restrict__ fc1_b, float* __restrict__ h1) {
  int og = blockIdx.x, b = blockIdx.y, tid = threadIdx.x;
  int wid = tid >> 6, lane = tid & 63;
  const float4* yv = (const float4*)(y + (size_t)b * 1024);
  float4 u[4];
#pragma unroll
  for (int r = 0; r < 4; r++) u[r] = yv[r * 64 + lane];
#pragma unroll 4
  for (int pass = 0; pass < 16; pass++) {
    int o = og * 64 + pass * 4 + wid;
    const float4* wr = (const float4*)(fc1_w + (size_t)o * 1024);
    float sa = 0, sb = 0, sc = 0, sd = 0;
#pragma unroll
    for (int r = 0; r < 4; r++) {
      float4 wv = wr[r * 64 + lane];
      sa = fmaf(wv.x, u[r].x, sa); sb = fmaf(wv.y, u[r].y, sb);
      sc = fmaf(wv.z, u[r].z, sc); sd = fmaf(wv.w, u[r].w, sd);
    }
    float s = (sa + sb) + (sc + sd);
#pragma unroll
    for (int d = 1; d < 64; d <<= 1) s += __shfl_xor(s, d);
    if (lane == 0) {
      float t = s + fc1_b[o];
      h1[(size_t)b * 512 + o] = LEAKY(t);
    }
  }
}

// ============================================================
// Kernel E2: fc2 -> heads. grid (B), 1024 thr (16 waves).
// ============================================================
__global__ __launch_bounds__(1024) void kE2(
    const float* __restrict__ h1, const float* __restrict__ fc2_w,
    const float* __restrict__ fc2_b,
    const float* __restrict__ fcr_w, const float* __restrict__ fcr_b,
    const float* __restrict__ fct_w, const float* __restrict__ fct_b,
    float* __restrict__ out) {
  __shared__ float h1l[512];
  __shared__ float h2[256];
  int b = blockIdx.x, tid = threadIdx.x;
  int w = tid >> 6, lane = tid & 63;
  if (tid < 128) {
    float4 v = ((const float4*)(h1 + (size_t)b * 512))[tid];
    ((float4*)h1l)[tid] = v;
  }
  __syncthreads();
  {  // fc2: 16 waves x 16 outputs, coalesced rows
    const float4* h1v = (const float4*)h1l;
    float4 u0 = h1v[lane], u1 = h1v[64 + lane];
#pragma unroll 2
    for (int pass = 0; pass < 16; pass++) {
      int o = w * 16 + pass;
      const float4* wr = (const float4*)(fc2_w + (size_t)o * 512);
      float4 w0 = wr[lane], w1 = wr[64 + lane];
      float sa = fmaf(w0.x, u0.x, 0.f), sb = fmaf(w0.y, u0.y, 0.f);
      float sc = fmaf(w0.z, u0.z, 0.f), sd = fmaf(w0.w, u0.w, 0.f);
      sa = fmaf(w1.x, u1.x, sa); sb = fmaf(w1.y, u1.y, sb);
      sc = fmaf(w1.z, u1.z, sc); sd = fmaf(w1.w, u1.w, sd);
      float s = (sa + sb) + (sc + sd);
#pragma unroll
      for (int d = 1; d < 64; d <<= 1) s += __shfl_xor(s, d);
      if (lane == 0) {
        float t = s + fc2_b[o];
        h2[o] = LEAKY(t);
      }
    }
  }
  __syncthreads();
  if (w < 7) {  // heads: wave-per-output
    bool isrot = w < 4;
    int o = isrot ? w : w - 4;
    const float4* wr = (const float4*)((isrot ? fcr_w : fct_w) + (size_t)o * 256);
    const float4* uv = (const float4*)h2;
    float4 wv = wr[lane];
    float4 u = uv[lane];
    float s = fmaf(wv.x, u.x, fmaf(wv.y, u.y, fmaf(wv.z, u.z, wv.w * u.w)));
#pragma unroll
    for (int d = 1; d < 64; d <<= 1) s += __shfl_xor(s, d);
    if (lane == 0) {
      float t = s + (isrot ? fcr_b[o] : fct_b[o]);
      out[isrot ? (b * 4 + o) : (128 + b * 3 + o)] = t;
    }
  }
}

extern "C" void kernel_launch(void* const* d_in, const int* in_sizes, int n_in,
                              void* d_out, int out_size, void* d_ws, size_t ws_size,
                              hipStream_t stream) {
  const float* coor    = (const float*)d_in[0];
  const float* region  = (const float*)d_in[1];
  const float* extents = (const float*)d_in[2];
  const float* w1 = (const float*)d_in[3];  const float* b1 = (const float*)d_in[4];
  const float* w2 = (const float*)d_in[5];  const float* b2 = (const float*)d_in[6];
  const float* w3 = (const float*)d_in[7];  const float* b3 = (const float*)d_in[8];
  const float* w_sp = (const float*)d_in[9];  const float* b_sp = (const float*)d_in[10];
  const float* fc1_w = (const float*)d_in[11]; const float* fc1_b = (const float*)d_in[12];
  const float* fc2_w = (const float*)d_in[13]; const float* fc2_b = (const float*)d_in[14];
  const float* fcr_w = (const float*)d_in[15]; const float* fcr_b = (const float*)d_in[16];
  const float* fct_w = (const float*)d_in[17]; const float* fct_b = (const float*)d_in[18];

  char* ws = (char*)d_ws;
  unsigned* pool = (unsigned*)(ws + OFF_POOL);
  unsigned short* wsp = (unsigned short*)(ws + OFF_WSP);
  float* y32  = (float*)(ws + OFF_Y32);
  float* y    = (float*)(ws + OFF_Y);
  float* h1   = (float*)(ws + OFF_H1);
  float* out  = (float*)d_out;

  kW<<<dim3(128), 256, 0, stream>>>(w2, w3, wsp, pool);
  kA<<<dim3(NTILES, NBATCH), 512, 0, stream>>>(coor, region, extents,
                                               w1, b1, b2, b3, wsp, pool);
  kC<<<dim3(32, 8), 256, 0, stream>>>(pool, w_sp, y32);
  kY<<<dim3(4, NBATCH), 256, 0, stream>>>(y32, b_sp, y);
  kE1<<<dim3(8, NBATCH), 256, 0, stream>>>(y, fc1_w, fc1_b, h1);
  kE2<<<dim3(NBATCH), 1024, 0, stream>>>(h1, fc2_w, fc2_b, fcr_w, fcr_b,
                                         fct_w, fct_b, out);
}